// Round 1
// baseline (113014.612 us; speedup 1.0000x reference)
//
#include <hip/hip_runtime.h>
#include <cstdint>
#include <cstring>
#include <cstddef>

#define L_ 2
#define H_ 1024
#define V_ 32000
#define B_ 16
#define T_ 256
#define BT_ 4096
#define EPS_ 1e-6f

typedef __attribute__((ext_vector_type(8))) short bf16x8;
typedef __attribute__((ext_vector_type(4))) short s16x4;
typedef __attribute__((ext_vector_type(4))) float f32x4;

__device__ __forceinline__ short f2bf(float f){
  uint32_t u; __builtin_memcpy(&u,&f,4);
  u += 0x7fffu + ((u>>16)&1u);
  return (short)(u>>16);
}

// ---------------- block reduction over 256 threads ----------------
__device__ __forceinline__ float block_sum256(float v, float* s4){
#pragma unroll
  for(int o=32;o;o>>=1) v += __shfl_down(v,o,64);
  int lane = threadIdx.x & 63, w = threadIdx.x >> 6;
  if(lane==0) s4[w]=v;
  __syncthreads();
  float r = s4[0]+s4[1]+s4[2]+s4[3];
  __syncthreads();
  return r;
}

// ---------------- embedding gather + LayerNorm (layer 0) ----------------
__global__ __launch_bounds__(256) void k_embed_ln(
    const float* __restrict__ E, const int* __restrict__ tok,
    const float* __restrict__ g, const float* __restrict__ b,
    float* __restrict__ x_emb, float* __restrict__ xn, short* __restrict__ xn_bf){
  __shared__ float s4[4];
  int row = blockIdx.x;                 // row = b*T + t
  int t = tok[row];
  const float4* src = (const float4*)(E + (size_t)t*H_);
  float4 v = src[threadIdx.x];
  ((float4*)(x_emb + (size_t)row*H_))[threadIdx.x] = v;
  float mean = block_sum256(v.x+v.y+v.z+v.w, s4) * (1.0f/H_);
  float d0=v.x-mean,d1=v.y-mean,d2=v.z-mean,d3=v.w-mean;
  float var = block_sum256(d0*d0+d1*d1+d2*d2+d3*d3, s4) * (1.0f/H_);
  float inv = 1.0f/(sqrtf(var)+EPS_);
  int c = threadIdx.x*4;
  float o0 = g[c+0]*(d0*inv)+b[c+0];
  float o1 = g[c+1]*(d1*inv)+b[c+1];
  float o2 = g[c+2]*(d2*inv)+b[c+2];
  float o3 = g[c+3]*(d3*inv)+b[c+3];
  ((float4*)(xn + (size_t)row*H_))[threadIdx.x] = make_float4(o0,o1,o2,o3);
  s16x4 ob = {f2bf(o0),f2bf(o1),f2bf(o2),f2bf(o3)};
  ((s16x4*)(xn_bf + (size_t)row*H_))[threadIdx.x] = ob;
}

// ---------------- LayerNorm for 16 rows (layer 1 input) ----------------
__global__ __launch_bounds__(256) void k_ln16(
    const float* __restrict__ X, const float* __restrict__ g,
    const float* __restrict__ b, float* __restrict__ Y){
  __shared__ float s4[4];
  int row = blockIdx.x;
  float4 v = ((const float4*)(X + (size_t)row*H_))[threadIdx.x];
  float mean = block_sum256(v.x+v.y+v.z+v.w, s4)*(1.0f/H_);
  float d0=v.x-mean,d1=v.y-mean,d2=v.z-mean,d3=v.w-mean;
  float var = block_sum256(d0*d0+d1*d1+d2*d2+d3*d3, s4)*(1.0f/H_);
  float inv = 1.0f/(sqrtf(var)+EPS_);
  int c = threadIdx.x*4;
  float4 o = make_float4(g[c]*(d0*inv)+b[c], g[c+1]*(d1*inv)+b[c+1],
                         g[c+2]*(d2*inv)+b[c+2], g[c+3]*(d3*inv)+b[c+3]);
  ((float4*)(Y + (size_t)row*H_))[threadIdx.x] = o;
}

// ---------------- transpose fp32 [R,C] -> bf16 [C,R] ----------------
__global__ __launch_bounds__(256) void k_transpose_bf(
    const float* __restrict__ src, short* __restrict__ dst, int Rr, int Cc){
  __shared__ float tile[32][33];
  int c0 = blockIdx.x*32, r0 = blockIdx.y*32;
  int tx = threadIdx.x & 31, ty = threadIdx.x >> 5;
#pragma unroll
  for(int i=0;i<32;i+=8)
    tile[ty+i][tx] = src[(size_t)(r0+ty+i)*Cc + c0+tx];
  __syncthreads();
#pragma unroll
  for(int i=0;i<32;i+=8)
    dst[(size_t)(c0+ty+i)*Rr + r0+tx] = f2bf(tile[tx][ty+i]);
}

// ---------------- fp32 -> bf16 flat convert ----------------
__global__ void k_f2bf_vec(const float* __restrict__ s, short* __restrict__ d, int n4){
  int i = blockIdx.x*blockDim.x + threadIdx.x;
  int st = gridDim.x*blockDim.x;
  for(; i<n4; i+=st){
    float4 v = ((const float4*)s)[i];
    s16x4 o = {f2bf(v.x),f2bf(v.y),f2bf(v.z),f2bf(v.w)};
    ((s16x4*)d)[i] = o;
  }
}

// ---------------- bf16 MFMA NT GEMM: C[M,N] = epi(A[M,K] @ Wt[N,K]^T) ----------------
// EPI: 0 plain->f32, 1 +bias->f32, 2 2*sigmoid(+bias)->f32, 3 relu(+bias)->bf16
template<int EPI>
__global__ __launch_bounds__(256) void k_mfma_nt(
    const short* __restrict__ A, const short* __restrict__ Wt,
    const float* __restrict__ bias, void* __restrict__ out,
    int M, int N, int K){
  int wid = threadIdx.x >> 6, lane = threadIdx.x & 63;
  int m0 = blockIdx.y*64;
  int n0 = blockIdx.x*128 + wid*32;
  int lr = lane & 15, kq = lane >> 4;
  const short* Ap = A + (size_t)(m0+lr)*K + kq*8;
  const short* Bp = Wt + (size_t)(n0+lr)*K + kq*8;
  f32x4 acc[4][2];
#pragma unroll
  for(int i=0;i<4;i++)
#pragma unroll
    for(int j=0;j<2;j++) acc[i][j] = (f32x4)0.0f;
  for(int k=0;k<K;k+=32){
    bf16x8 a[4], b[2];
#pragma unroll
    for(int mi=0;mi<4;mi++) a[mi] = *(const bf16x8*)(Ap + (size_t)mi*16*K + k);
#pragma unroll
    for(int ni=0;ni<2;ni++) b[ni] = *(const bf16x8*)(Bp + (size_t)ni*16*K + k);
#pragma unroll
    for(int mi=0;mi<4;mi++)
#pragma unroll
      for(int ni=0;ni<2;ni++)
        acc[mi][ni] = __builtin_amdgcn_mfma_f32_16x16x32_bf16(a[mi], b[ni], acc[mi][ni], 0,0,0);
  }
#pragma unroll
  for(int mi=0;mi<4;mi++)
#pragma unroll
    for(int ni=0;ni<2;ni++)
#pragma unroll
      for(int r=0;r<4;r++){
        int row = m0 + mi*16 + kq*4 + r;
        int col = n0 + ni*16 + lr;
        float s = acc[mi][ni][r];
        if(EPI==0){ ((float*)out)[(size_t)row*N+col] = s; }
        else if(EPI==1){ ((float*)out)[(size_t)row*N+col] = s + bias[col]; }
        else if(EPI==2){ float z = s + bias[col];
                         ((float*)out)[(size_t)row*N+col] = 2.0f/(1.0f+expf(-z)); }
        else { float z = fmaxf(s + bias[col], 0.0f);
               ((short*)out)[(size_t)row*N+col] = f2bf(z); }
      }
}

// ---------------- small sequential GEMM: [16,K] @ [K,N] with fused epilogue ----------------
struct SeqArgs {
  const float* A1; int lda1;
  const float* A2; int lda2;          // optional elementwise multiplier on A
  const float* W;  int ldw; int K;    // W row-major [K, ldw]
  const float* b1; const float* b2;   // biases indexed by col
  const float* m1; int ldm1;          // epilogue gate operand(s): out = m * 2*sigmoid(s)
  const float* m2; int ldm2;
  const float* r1; int ldr1;          // residual adds
  const float* r2; int ldr2;
  const float* r3; int ldr3;
  float* outF; short* outB; int ldo;
  int mode;                           // 0 plain, 1 mul*2sig, 2 tanh, 3 relu
};

__global__ __launch_bounds__(256) void k_seq_gemm(SeqArgs g){
  __shared__ float Ae[16][64];
  __shared__ float red[16][16][16];
  int n0 = blockIdx.x*16;
  int tid = threadIdx.x;
  int c = tid & 15, kl = tid >> 4;
  float acc[16];
#pragma unroll
  for(int r=0;r<16;r++) acc[r]=0.f;
  for(int kb=0; kb<g.K; kb+=64){
    __syncthreads();
#pragma unroll
    for(int i=0;i<4;i++){
      int idx = tid + i*256;
      int r = idx >> 6, kk = idx & 63;
      float a = g.A1[(size_t)r*g.lda1 + kb + kk];
      if(g.A2) a *= g.A2[(size_t)r*g.lda2 + kb + kk];
      Ae[r][kk] = a;
    }
    __syncthreads();
#pragma unroll
    for(int ks=0;ks<4;ks++){
      int kk = ks*16 + kl;
      float w = g.W[(size_t)(kb+kk)*g.ldw + n0 + c];
#pragma unroll
      for(int r=0;r<16;r++) acc[r] += Ae[r][kk] * w;
    }
  }
#pragma unroll
  for(int r=0;r<16;r++) red[kl][r][c] = acc[r];
  __syncthreads();
  int rr = tid >> 4;
  float s = 0.f;
#pragma unroll
  for(int k2=0;k2<16;k2++) s += red[k2][rr][c];
  int col = n0 + c;
  if(g.b1) s += g.b1[col];
  if(g.b2) s += g.b2[col];
  if(g.mode==1){
    float m = g.m1[(size_t)rr*g.ldm1 + col];
    if(g.m2) m *= g.m2[(size_t)rr*g.ldm2 + col];
    s = m * 2.0f * (1.0f/(1.0f+expf(-s)));
  } else if(g.mode==2){ s = tanhf(s); }
  else if(g.mode==3){ s = fmaxf(s,0.f); }
  if(g.r1) s += g.r1[(size_t)rr*g.ldr1 + col];
  if(g.r2) s += g.r2[(size_t)rr*g.ldr2 + col];
  if(g.r3) s += g.r3[(size_t)rr*g.ldr3 + col];
  if(g.outF) g.outF[(size_t)rr*g.ldo + col] = s;
  if(g.outB) g.outB[(size_t)rr*g.ldo + col] = f2bf(s);
}

extern "C" void kernel_launch(void* const* d_in, const int* in_sizes, int n_in,
                              void* d_out, int out_size, void* d_ws, size_t ws_size,
                              hipStream_t stream){
  const float* E    = (const float*)d_in[0];
  const float* ln_g = (const float*)d_in[1];
  const float* ln_b = (const float*)d_in[2];
  const float* Wm   = (const float*)d_in[3];   // [2,3,H,H]
  const float* Wmb  = (const float*)d_in[4];   // [2,3,H]
  const float* Wh   = (const float*)d_in[5];   // [2,2H,H]
  const float* Whb  = (const float*)d_in[6];
  const float* bh   = (const float*)d_in[7];
  const float* Wy   = (const float*)d_in[8];   // [2,H,H]
  const float* Wyb  = (const float*)d_in[9];
  const float* by   = (const float*)d_in[10];
  const float* W1   = (const float*)d_in[11];  // [2,H,4H]
  const float* W1b  = (const float*)d_in[12];  // [2,4H]
  const float* W2   = (const float*)d_in[13];  // [2,4H,H]
  const float* W2b  = (const float*)d_in[14];
  const int*   xx   = (const int*)d_in[15];
  float* outF = (float*)d_out;
  (void)in_sizes; (void)n_in; (void)out_size; (void)ws_size;

  char* p = (char*)d_ws;
  auto alloc = [&](size_t bytes)->void*{ void* r=(void*)p; p += (bytes+255)&~(size_t)255; return r; };
  float* x_emb = (float*)alloc((size_t)BT_*H_*4);
  float* xn0   = (float*)alloc((size_t)BT_*H_*4);
  float* mg0   = (float*)alloc((size_t)BT_*H_*4);
  float* ff0   = (float*)alloc((size_t)BT_*H_*4);
  short* xn0_bf= (short*)alloc((size_t)BT_*H_*2);
  short* t1c   = (short*)alloc((size_t)1024*4*H_*2);
  short* WmT   = (short*)alloc((size_t)H_*H_*2);
  short* W1T   = (short*)alloc((size_t)4*H_*H_*2);
  short* W2T   = (short*)alloc((size_t)4*H_*H_*2);
  short* E_bf  = (short*)alloc((size_t)V_*H_*2);
  short* dec_bf= (short*)alloc((size_t)BT_*H_*2);
  float* h0    = (float*)alloc((size_t)16*H_*4);
  float* h1    = (float*)alloc((size_t)16*H_*4);
  float* xcat0 = (float*)alloc((size_t)16*2*H_*4);
  float* out0  = (float*)alloc((size_t)16*H_*4);
  float* xn1   = (float*)alloc((size_t)16*H_*4);
  float* hmog1 = (float*)alloc((size_t)16*H_*4);
  float* xcat1 = (float*)alloc((size_t)16*2*H_*4);
  float* t1s   = (float*)alloc((size_t)16*4*H_*4);
  float* ffy1  = (float*)alloc((size_t)16*H_*4);

  const int ldT = T_*H_;
  const size_t H2 = (size_t)H_*H_;

  // zero h states (h0,h1 contiguous)
  hipMemsetAsync(h0, 0, 2*16*H_*sizeof(float), stream);

  // ---- precompute phase ----
  k_embed_ln<<<BT_,256,0,stream>>>(E, xx, ln_g, ln_b, x_emb, xn0, xn0_bf);
  k_transpose_bf<<<dim3(32,32),256,0,stream>>>(Wm, WmT, H_, H_);
  k_mfma_nt<2><<<dim3(1024/128, BT_/64),256,0,stream>>>(xn0_bf, WmT, Wmb, mg0, BT_, 1024, 1024);
  k_transpose_bf<<<dim3(128,32),256,0,stream>>>(W1, W1T, H_, 4*H_);
  k_transpose_bf<<<dim3(32,128),256,0,stream>>>(W2, W2T, 4*H_, H_);
  for(int cb=0;cb<4;cb++){
    k_mfma_nt<3><<<dim3(4096/128, 1024/64),256,0,stream>>>(
        xn0_bf + (size_t)cb*1024*H_, W1T, W1b, t1c, 1024, 4096, 1024);
    k_mfma_nt<1><<<dim3(1024/128, 1024/64),256,0,stream>>>(
        t1c, W2T, W2b, ff0 + (size_t)cb*1024*H_, 1024, 1024, 4096);
  }
  k_f2bf_vec<<<2048,256,0,stream>>>(E, E_bf, (V_*H_)/4);

  // ---- sequential recurrence ----
  auto seq = [&](int N, int K, const float* A1,int lda1, const float* A2,int lda2,
                 const float* W,int ldw, const float* b1,const float* b2, int mode,
                 const float* m1,int ldm1,const float* m2,int ldm2,
                 const float* r1,int ldr1,const float* r2,int ldr2,const float* r3,int ldr3,
                 float* oF, short* oB, int ldo){
    SeqArgs g{};
    g.A1=A1; g.lda1=lda1; g.A2=A2; g.lda2=lda2; g.W=W; g.ldw=ldw; g.K=K;
    g.b1=b1; g.b2=b2; g.mode=mode;
    g.m1=m1; g.ldm1=ldm1; g.m2=m2; g.ldm2=ldm2;
    g.r1=r1; g.ldr1=ldr1; g.r2=r2; g.ldr2=ldr2; g.r3=r3; g.ldr3=ldr3;
    g.outF=oF; g.outB=oB; g.ldo=ldo;
    k_seq_gemm<<<N/16, 256, 0, stream>>>(g);
  };

  for(int t=0;t<T_;t++){
    const float* xemb_t = x_emb + (size_t)t*H_;
    const float* xn0_t  = xn0 + (size_t)t*H_;
    const float* mg0_t  = mg0 + (size_t)t*H_;
    const float* ff0_t  = ff0 + (size_t)t*H_;
    // ---- layer 0 (mg round 0 precomputed) ----
    // S1: x_mog0 = xn0_t * 2sig((h0*mg0_t) @ Wm[0,1] + b)
    seq(1024,1024, h0,H_, mg0_t,ldT, Wm+1*H2,H_, Wmb+1*H_,nullptr, 1,
        xn0_t,ldT, nullptr,0, nullptr,0,nullptr,0,nullptr,0, xcat0,nullptr,2*H_);
    // S2: h_mog0 = (h0*mg0_t) * 2sig(x_mog0 @ Wm[0,2] + b)
    seq(1024,1024, xcat0,2*H_, nullptr,0, Wm+2*H2,H_, Wmb+2*H_,nullptr, 1,
        h0,H_, mg0_t,ldT, nullptr,0,nullptr,0,nullptr,0, xcat0+H_,nullptr,2*H_);
    // S3: h0' = tanh([x_mog0,h_mog0] @ Wh0 + Whb0 + bh0)
    seq(1024,2048, xcat0,2*H_, nullptr,0, Wh,H_, Whb,bh, 2,
        nullptr,0,nullptr,0, nullptr,0,nullptr,0,nullptr,0, h0,nullptr,H_);
    // S4: out0 = h0' @ Wy0 + Wyb0 + by0 + x_emb_t + ff0_t
    seq(1024,1024, h0,H_, nullptr,0, Wy,H_, Wyb,by, 0,
        nullptr,0,nullptr,0, xemb_t,ldT, ff0_t,ldT, nullptr,0, out0,nullptr,H_);
    // S4b: xn1 = LN(out0)
    k_ln16<<<16,256,0,stream>>>(out0, ln_g+H_, ln_b+H_, xn1);
    // ---- layer 1 ----
    // S5a: h_mog1 = h1 * 2sig(xn1 @ Wm[1,0] + b)
    seq(1024,1024, xn1,H_, nullptr,0, Wm+3*H2,H_, Wmb+3*H_,nullptr, 1,
        h1,H_, nullptr,0, nullptr,0,nullptr,0,nullptr,0, hmog1,nullptr,H_);
    // S5b: t1s = relu(xn1 @ W1_1 + b)
    seq(4096,1024, xn1,H_, nullptr,0, W1+(size_t)H_*4*H_,4*H_, W1b+4*H_,nullptr, 3,
        nullptr,0,nullptr,0, nullptr,0,nullptr,0,nullptr,0, t1s,nullptr,4*H_);
    // S6a: x_mog1 = xn1 * 2sig(h_mog1 @ Wm[1,1] + b)
    seq(1024,1024, hmog1,H_, nullptr,0, Wm+4*H2,H_, Wmb+4*H_,nullptr, 1,
        xn1,H_, nullptr,0, nullptr,0,nullptr,0,nullptr,0, xcat1,nullptr,2*H_);
    // S6b: ffy1 = t1s @ W2_1 + b
    seq(1024,4096, t1s,4*H_, nullptr,0, W2+(size_t)4*H_*H_,H_, W2b+H_,nullptr, 0,
        nullptr,0,nullptr,0, nullptr,0,nullptr,0,nullptr,0, ffy1,nullptr,H_);
    // S7: h_mog1b = h_mog1 * 2sig(x_mog1 @ Wm[1,2] + b)
    seq(1024,1024, xcat1,2*H_, nullptr,0, Wm+5*H2,H_, Wmb+5*H_,nullptr, 1,
        hmog1,H_, nullptr,0, nullptr,0,nullptr,0,nullptr,0, xcat1+H_,nullptr,2*H_);
    // S8: h1' = tanh([x_mog1,h_mog1b] @ Wh1 + Whb1 + bh1)
    seq(1024,2048, xcat1,2*H_, nullptr,0, Wh+2*H2,H_, Whb+H_,bh+H_, 2,
        nullptr,0,nullptr,0, nullptr,0,nullptr,0,nullptr,0, h1,nullptr,H_);
    // S9: dec_t = h1' @ Wy1 + Wyb1 + by1 + out0 + x_emb_t + ffy1  (store bf16)
    seq(1024,1024, h1,H_, nullptr,0, Wy+H2,H_, Wyb+H_,by+H_, 0,
        nullptr,0,nullptr,0, out0,H_, xemb_t,ldT, ffy1,H_, nullptr, dec_bf+(size_t)t*H_, ldT);
  }

  // ---- logits: [4096,1024] @ E^T -> [4096,32000] fp32 ----
  k_mfma_nt<0><<<dim3(V_/128, BT_/64),256,0,stream>>>(dec_bf, E_bf, nullptr, outF, BT_, V_, 1024);
}

// Round 2
// 17397.256 us; speedup vs baseline: 6.4961x; 6.4961x over previous
//
#include <hip/hip_runtime.h>
#include <cstdint>
#include <cstring>
#include <cstddef>

#define L_ 2
#define H_ 1024
#define V_ 32000
#define B_ 16
#define T_ 256
#define BT_ 4096
#define EPS_ 1e-6f
#define NBLK 64

typedef __attribute__((ext_vector_type(8))) short bf16x8;
typedef __attribute__((ext_vector_type(4))) short s16x4;
typedef __attribute__((ext_vector_type(4))) float f32x4;

__device__ __forceinline__ short f2bf(float f){
  uint32_t u; __builtin_memcpy(&u,&f,4);
  u += 0x7fffu + ((u>>16)&1u);
  return (short)(u>>16);
}
__device__ __forceinline__ float bf2f(short s){
  uint32_t u = ((uint32_t)(unsigned short)s)<<16;
  float f; __builtin_memcpy(&f,&u,4); return f;
}

// ---------------- block reduction over 256 threads ----------------
__device__ __forceinline__ float block_sum256(float v, float* s4){
#pragma unroll
  for(int o=32;o;o>>=1) v += __shfl_down(v,o,64);
  int lane = threadIdx.x & 63, w = threadIdx.x >> 6;
  if(lane==0) s4[w]=v;
  __syncthreads();
  float r = s4[0]+s4[1]+s4[2]+s4[3];
  __syncthreads();
  return r;
}

// ---------------- embedding gather + LayerNorm (layer 0), time-major rows ----------------
__global__ __launch_bounds__(256) void k_embed_ln(
    const float* __restrict__ E, const int* __restrict__ tok,
    const float* __restrict__ g, const float* __restrict__ b,
    short* __restrict__ x_emb_bf, short* __restrict__ xn_bf){
  __shared__ float s4[4];
  int row = blockIdx.x;              // row = t*16 + b
  int t = row >> 4, bb = row & 15;
  int tk = tok[bb*T_ + t];
  float4 v = ((const float4*)(E + (size_t)tk*H_))[threadIdx.x];
  float mean = block_sum256(v.x+v.y+v.z+v.w, s4) * (1.0f/H_);
  float d0=v.x-mean,d1=v.y-mean,d2=v.z-mean,d3=v.w-mean;
  float var = block_sum256(d0*d0+d1*d1+d2*d2+d3*d3, s4) * (1.0f/H_);
  float inv = 1.0f/(sqrtf(var)+EPS_);
  int c = threadIdx.x*4;
  s16x4 eb = {f2bf(v.x),f2bf(v.y),f2bf(v.z),f2bf(v.w)};
  ((s16x4*)(x_emb_bf + (size_t)row*H_))[threadIdx.x] = eb;
  s16x4 ob = {f2bf(g[c+0]*(d0*inv)+b[c+0]), f2bf(g[c+1]*(d1*inv)+b[c+1]),
              f2bf(g[c+2]*(d2*inv)+b[c+2]), f2bf(g[c+3]*(d3*inv)+b[c+3])};
  ((s16x4*)(xn_bf + (size_t)row*H_))[threadIdx.x] = ob;
}

// ---------------- LayerNorm rows f32 -> bf16 ----------------
__global__ __launch_bounds__(256) void k_ln_bf(
    const float* __restrict__ X, const float* __restrict__ g,
    const float* __restrict__ b, short* __restrict__ Y){
  __shared__ float s4[4];
  int row = blockIdx.x;
  float4 v = ((const float4*)(X + (size_t)row*H_))[threadIdx.x];
  float mean = block_sum256(v.x+v.y+v.z+v.w, s4)*(1.0f/H_);
  float d0=v.x-mean,d1=v.y-mean,d2=v.z-mean,d3=v.w-mean;
  float var = block_sum256(d0*d0+d1*d1+d2*d2+d3*d3, s4)*(1.0f/H_);
  float inv = 1.0f/(sqrtf(var)+EPS_);
  int c = threadIdx.x*4;
  s16x4 o = {f2bf(g[c]*(d0*inv)+b[c]), f2bf(g[c+1]*(d1*inv)+b[c+1]),
             f2bf(g[c+2]*(d2*inv)+b[c+2]), f2bf(g[c+3]*(d3*inv)+b[c+3])};
  ((s16x4*)(Y + (size_t)row*H_))[threadIdx.x] = o;
}

// ---------------- transpose fp32 [R,C] -> bf16 [C,R] ----------------
__global__ __launch_bounds__(256) void k_transpose_bf(
    const float* __restrict__ src, short* __restrict__ dst, int Rr, int Cc){
  __shared__ float tile[32][33];
  int c0 = blockIdx.x*32, r0 = blockIdx.y*32;
  int tx = threadIdx.x & 31, ty = threadIdx.x >> 5;
#pragma unroll
  for(int i=0;i<32;i+=8)
    tile[ty+i][tx] = src[(size_t)(r0+ty+i)*Cc + c0+tx];
  __syncthreads();
#pragma unroll
  for(int i=0;i<32;i+=8)
    dst[(size_t)(c0+ty+i)*Rr + r0+tx] = f2bf(tile[tx][ty+i]);
}

// ---------------- fp32 -> bf16 flat convert ----------------
__global__ void k_f2bf_vec(const float* __restrict__ s, short* __restrict__ d, int n4){
  int i = blockIdx.x*blockDim.x + threadIdx.x;
  int st = gridDim.x*blockDim.x;
  for(; i<n4; i+=st){
    float4 v = ((const float4*)s)[i];
    s16x4 o = {f2bf(v.x),f2bf(v.y),f2bf(v.z),f2bf(v.w)};
    ((s16x4*)d)[i] = o;
  }
}

// ---------------- bf16 MFMA NT GEMM, generalized epilogue ----------------
// C[M,N] = act(A@Wt^T + b1 + b2) + rf + rb1 + rb2 ; out f32 or bf16
// ACT: 0 none, 1 2*sigmoid, 2 relu.  REMAP: out row = (row&15)*T_ + (row>>4)
template<int ACT, int OBF, int REMAP>
__global__ __launch_bounds__(256) void k_mfma_nt(
    const short* __restrict__ A, const short* __restrict__ Wt,
    const float* __restrict__ b1, const float* __restrict__ b2,
    const float* __restrict__ rf, const short* __restrict__ rb1,
    const short* __restrict__ rb2, void* __restrict__ out,
    int M, int N, int K){
  int wid = threadIdx.x >> 6, lane = threadIdx.x & 63;
  int m0 = blockIdx.y*64;
  int n0 = blockIdx.x*128 + wid*32;
  int lr = lane & 15, kq = lane >> 4;
  const short* Ap = A + (size_t)(m0+lr)*K + kq*8;
  const short* Bp = Wt + (size_t)(n0+lr)*K + kq*8;
  f32x4 acc[4][2];
#pragma unroll
  for(int i=0;i<4;i++)
#pragma unroll
    for(int j=0;j<2;j++) acc[i][j] = (f32x4)0.0f;
  for(int k=0;k<K;k+=32){
    bf16x8 a[4], b[2];
#pragma unroll
    for(int mi=0;mi<4;mi++) a[mi] = *(const bf16x8*)(Ap + (size_t)mi*16*K + k);
#pragma unroll
    for(int ni=0;ni<2;ni++) b[ni] = *(const bf16x8*)(Bp + (size_t)ni*16*K + k);
#pragma unroll
    for(int mi=0;mi<4;mi++)
#pragma unroll
      for(int ni=0;ni<2;ni++)
        acc[mi][ni] = __builtin_amdgcn_mfma_f32_16x16x32_bf16(a[mi], b[ni], acc[mi][ni], 0,0,0);
  }
#pragma unroll
  for(int mi=0;mi<4;mi++)
#pragma unroll
    for(int ni=0;ni<2;ni++)
#pragma unroll
      for(int r=0;r<4;r++){
        int row = m0 + mi*16 + kq*4 + r;
        int col = n0 + ni*16 + lr;
        float s = acc[mi][ni][r];
        if(b1) s += b1[col];
        if(b2) s += b2[col];
        if(ACT==1) s = 2.0f/(1.0f+expf(-s));
        else if(ACT==2) s = fmaxf(s, 0.0f);
        if(rf)  s += rf[(size_t)row*N+col];
        if(rb1) s += bf2f(rb1[(size_t)row*N+col]);
        if(rb2) s += bf2f(rb2[(size_t)row*N+col]);
        size_t orow = REMAP ? ((size_t)(row&15)*T_ + (row>>4)) : (size_t)row;
        if(OBF) ((short*)out)[orow*N+col] = f2bf(s);
        else    ((float*)out)[orow*N+col] = s;
      }
}

// ---------------- device-wide spin barrier (64 blocks, agent scope) ----------------
__device__ __forceinline__ void gbar(unsigned* bar){
  __syncthreads();
  if(threadIdx.x==0){
    __threadfence();
    unsigned gen = __hip_atomic_load(&bar[1], __ATOMIC_RELAXED, __HIP_MEMORY_SCOPE_AGENT);
    unsigned arr = __hip_atomic_fetch_add(&bar[0], 1u, __ATOMIC_ACQ_REL, __HIP_MEMORY_SCOPE_AGENT);
    if(arr == NBLK-1u){
      __hip_atomic_store(&bar[0], 0u, __ATOMIC_RELAXED, __HIP_MEMORY_SCOPE_AGENT);
      __hip_atomic_store(&bar[1], gen+1u, __ATOMIC_RELEASE, __HIP_MEMORY_SCOPE_AGENT);
    } else {
      while(__hip_atomic_load(&bar[1], __ATOMIC_ACQUIRE, __HIP_MEMORY_SCOPE_AGENT) == gen)
        __builtin_amdgcn_s_sleep(2);
    }
  }
  __syncthreads();
}

// ---------------- persistent recurrence phase kernel ----------------
// per t: G1: xm = xn[t] .* 2sig((h .* g[t]) @ Wm1T^T + bm1)
//        G2: hm = (h .* g[t]) .* 2sig(xm @ Wm2T^T + bm2)
//        G3: h  = tanh([xm,hm] @ WhT^T + bh1 + bh2) -> h, h_all[t]
struct PhaseArgs {
  const short* xn_all;   // [T,16,1024] bf16
  const short* gate_all; // [T,16,1024] bf16
  const short* Wm1T;     // [1024,1024]
  const float* bm1;
  const short* Wm2T;
  const float* bm2;
  const short* WhT;      // [1024,2048]
  const float* bh1; const float* bh2;
  short* h;              // [16,1024] bf16 state
  short* xcat;           // [16,2048] bf16
  short* h_all;          // [T,16,1024] bf16
  unsigned* bar;
};

__global__ __launch_bounds__(256,1) void k_phase(PhaseArgs P){
  __shared__ float red[4][16][16];
  const int tid = threadIdx.x;
  const int wid = tid>>6, lane = tid&63, lr = lane&15, kq = lane>>4;
  const int n0 = blockIdx.x*16;
  const int er = tid>>4, ec = tid&15;
  for(int t=0;t<T_;t++){
    const short* xn_t = P.xn_all   + (size_t)t*(16*H_);
    const short* g_t  = P.gate_all + (size_t)t*(16*H_);
    // ---- G1 ----
    {
      f32x4 acc = (f32x4)0.0f;
      const int kb = wid*256 + kq*8;
#pragma unroll
      for(int kk=0;kk<256;kk+=32){
        const int k = kb+kk;
        bf16x8 hv = *(const bf16x8*)(P.h + lr*H_ + k);
        bf16x8 gv = *(const bf16x8*)(g_t + lr*H_ + k);
        bf16x8 av;
#pragma unroll
        for(int j=0;j<8;j++) av[j] = f2bf(bf2f(hv[j])*bf2f(gv[j]));
        bf16x8 bv = *(const bf16x8*)(P.Wm1T + (size_t)(n0+lr)*H_ + k);
        acc = __builtin_amdgcn_mfma_f32_16x16x32_bf16(av,bv,acc,0,0,0);
      }
#pragma unroll
      for(int r=0;r<4;r++) red[wid][kq*4+r][lr] = acc[r];
      __syncthreads();
      float s = red[0][er][ec]+red[1][er][ec]+red[2][er][ec]+red[3][er][ec];
      s += P.bm1[n0+ec];
      float gate = 2.0f/(1.0f+expf(-s));
      P.xcat[er*2048 + n0+ec] = f2bf(bf2f(xn_t[er*H_ + n0+ec]) * gate);
    }
    gbar(P.bar);
    // ---- G2 ----
    {
      f32x4 acc = (f32x4)0.0f;
      const int kb = wid*256 + kq*8;
#pragma unroll
      for(int kk=0;kk<256;kk+=32){
        const int k = kb+kk;
        bf16x8 av = *(const bf16x8*)(P.xcat + lr*2048 + k);
        bf16x8 bv = *(const bf16x8*)(P.Wm2T + (size_t)(n0+lr)*H_ + k);
        acc = __builtin_amdgcn_mfma_f32_16x16x32_bf16(av,bv,acc,0,0,0);
      }
#pragma unroll
      for(int r=0;r<4;r++) red[wid][kq*4+r][lr] = acc[r];
      __syncthreads();
      float s = red[0][er][ec]+red[1][er][ec]+red[2][er][ec]+red[3][er][ec];
      s += P.bm2[n0+ec];
      float gate = 2.0f/(1.0f+expf(-s));
      float hm = bf2f(P.h[er*H_ + n0+ec]) * bf2f(g_t[er*H_ + n0+ec]) * gate;
      P.xcat[er*2048 + 1024 + n0+ec] = f2bf(hm);
    }
    gbar(P.bar);
    // ---- G3 (K=2048) ----
    {
      f32x4 acc = (f32x4)0.0f;
      const int kb = wid*512 + kq*8;
#pragma unroll
      for(int kk=0;kk<512;kk+=32){
        const int k = kb+kk;
        bf16x8 av = *(const bf16x8*)(P.xcat + lr*2048 + k);
        bf16x8 bv = *(const bf16x8*)(P.WhT + (size_t)(n0+lr)*2048 + k);
        acc = __builtin_amdgcn_mfma_f32_16x16x32_bf16(av,bv,acc,0,0,0);
      }
#pragma unroll
      for(int r=0;r<4;r++) red[wid][kq*4+r][lr] = acc[r];
      __syncthreads();
      float s = red[0][er][ec]+red[1][er][ec]+red[2][er][ec]+red[3][er][ec];
      s += P.bh1[n0+ec] + P.bh2[n0+ec];
      short hb = f2bf(tanhf(s));
      P.h[er*H_ + n0+ec] = hb;
      P.h_all[(size_t)t*(16*H_) + er*H_ + n0+ec] = hb;
    }
    gbar(P.bar);
  }
}

extern "C" void kernel_launch(void* const* d_in, const int* in_sizes, int n_in,
                              void* d_out, int out_size, void* d_ws, size_t ws_size,
                              hipStream_t stream){
  const float* E    = (const float*)d_in[0];
  const float* ln_g = (const float*)d_in[1];
  const float* ln_b = (const float*)d_in[2];
  const float* Wm   = (const float*)d_in[3];   // [2,3,H,H]
  const float* Wmb  = (const float*)d_in[4];   // [2,3,H]
  const float* Wh   = (const float*)d_in[5];   // [2,2H,H]
  const float* Whb  = (const float*)d_in[6];
  const float* bh   = (const float*)d_in[7];
  const float* Wy   = (const float*)d_in[8];   // [2,H,H]
  const float* Wyb  = (const float*)d_in[9];
  const float* by   = (const float*)d_in[10];
  const float* W1   = (const float*)d_in[11];  // [2,H,4H]
  const float* W1b  = (const float*)d_in[12];  // [2,4H]
  const float* W2   = (const float*)d_in[13];  // [2,4H,H]
  const float* W2b  = (const float*)d_in[14];
  const int*   xx   = (const int*)d_in[15];
  float* outF = (float*)d_out;
  (void)in_sizes; (void)n_in; (void)out_size; (void)ws_size;

  const size_t H2 = (size_t)H_*H_;
  char* p = (char*)d_ws;
  auto alloc = [&](size_t bytes)->void*{ void* r=(void*)p; p += (bytes+255)&~(size_t)255; return r; };

  // persistent region
  short* x_emb_bf = (short*)alloc((size_t)BT_*H_*2);
  short* xn0_bf   = (short*)alloc((size_t)BT_*H_*2);
  short* mg0_bf   = (short*)alloc((size_t)BT_*H_*2);
  short* ff0_bf   = (short*)alloc((size_t)BT_*H_*2);
  float* out0     = (float*)alloc((size_t)BT_*H_*4);
  short* xn1_bf   = (short*)alloc((size_t)BT_*H_*2);
  short* g1_bf    = (short*)alloc((size_t)BT_*H_*2);
  short* ffy1r_bf = (short*)alloc((size_t)BT_*H_*2);
  short* h0_all   = (short*)alloc((size_t)BT_*H_*2);
  short* h1_all   = (short*)alloc((size_t)BT_*H_*2);
  short* dec_bf   = (short*)alloc((size_t)BT_*H_*2);
  // zero-init region (contiguous): h0, h1, xcat, bar
  char*  z0   = p;
  short* h0   = (short*)alloc((size_t)16*H_*2);
  short* h1   = (short*)alloc((size_t)16*H_*2);
  short* xcat = (short*)alloc((size_t)16*2*H_*2);
  unsigned* bar = (unsigned*)alloc(256);
  size_t zbytes = (size_t)(p - z0);
  // weight region (dead after S9) — E_bf overlays it at the end
  char*  wreg = p;
  short* WmT = (short*)alloc(6*H2*2);          // [6][1024][1024]
  short* WhT = (short*)alloc(2*(size_t)H_*2*H_*2); // [2][1024][2048]
  short* WyT = (short*)alloc(2*H2*2);
  short* W1T = (short*)alloc(2*(size_t)4*H_*H_*2); // [2][4096][1024]
  short* W2T = (short*)alloc(2*(size_t)H_*4*H_*2); // [2][1024][4096]
  short* t1  = (short*)alloc((size_t)1024*4*H_*2); // FFN chunk buffer
  short* E_bf = (short*)wreg;                  // overlay: 62.5MB <= 64MB region

  hipMemsetAsync(z0, 0, zbytes, stream);

  // ---- precompute ----
  k_embed_ln<<<BT_,256,0,stream>>>(E, xx, ln_g, ln_b, x_emb_bf, xn0_bf);
  for(int i=0;i<6;i++)
    k_transpose_bf<<<dim3(32,32),256,0,stream>>>(Wm+i*H2, WmT+i*H2, H_, H_);
  for(int l=0;l<2;l++){
    k_transpose_bf<<<dim3(32,64),256,0,stream>>>(Wh+(size_t)l*2*H2, WhT+(size_t)l*2*H2, 2*H_, H_);
    k_transpose_bf<<<dim3(32,32),256,0,stream>>>(Wy+(size_t)l*H2, WyT+(size_t)l*H2, H_, H_);
    k_transpose_bf<<<dim3(128,32),256,0,stream>>>(W1+(size_t)l*4*H2, W1T+(size_t)l*4*H2, H_, 4*H_);
    k_transpose_bf<<<dim3(32,128),256,0,stream>>>(W2+(size_t)l*4*H2, W2T+(size_t)l*4*H2, 4*H_, H_);
  }
  // mg0 = 2sig(xn0 @ Wm[0,0]^T + b)
  k_mfma_nt<1,1,0><<<dim3(8,64),256,0,stream>>>(xn0_bf, WmT, Wmb, nullptr,
      nullptr,nullptr,nullptr, mg0_bf, BT_, H_, H_);
  // layer-0 FFN (chunked): ff0 = relu(xn0@W1_0+b)@W2_0 + b
  for(int cb=0;cb<4;cb++){
    k_mfma_nt<2,1,0><<<dim3(32,16),256,0,stream>>>(xn0_bf+(size_t)cb*1024*H_, W1T, W1b, nullptr,
        nullptr,nullptr,nullptr, t1, 1024, 4*H_, H_);
    k_mfma_nt<0,1,0><<<dim3(8,16),256,0,stream>>>(t1, W2T, W2b, nullptr,
        nullptr,nullptr,nullptr, ff0_bf+(size_t)cb*1024*H_, 1024, H_, 4*H_);
  }

  // ---- phase A: layer-0 recurrence ----
  PhaseArgs PA{};
  PA.xn_all=xn0_bf; PA.gate_all=mg0_bf;
  PA.Wm1T=WmT+1*H2; PA.bm1=Wmb+1*H_;
  PA.Wm2T=WmT+2*H2; PA.bm2=Wmb+2*H_;
  PA.WhT=WhT; PA.bh1=Whb; PA.bh2=bh;
  PA.h=h0; PA.xcat=xcat; PA.h_all=h0_all; PA.bar=bar;
  k_phase<<<NBLK,256,0,stream>>>(PA);

  // ---- batched middle ----
  // out0 = h0_all@Wy0^T + Wyb0 + by0 + x_emb + ff0   (f32)
  k_mfma_nt<0,0,0><<<dim3(8,64),256,0,stream>>>(h0_all, WyT, Wyb, by,
      nullptr, x_emb_bf, ff0_bf, out0, BT_, H_, H_);
  // xn1 = LN(out0)
  k_ln_bf<<<BT_,256,0,stream>>>(out0, ln_g+H_, ln_b+H_, xn1_bf);
  // g1 = 2sig(xn1 @ Wm[1,0]^T + b)
  k_mfma_nt<1,1,0><<<dim3(8,64),256,0,stream>>>(xn1_bf, WmT+3*H2, Wmb+3*H_, nullptr,
      nullptr,nullptr,nullptr, g1_bf, BT_, H_, H_);
  // layer-1 FFN (chunked) with fused residual: ffy1r = t1@W2_1 + b + out0 + x_emb
  for(int cb=0;cb<4;cb++){
    k_mfma_nt<2,1,0><<<dim3(32,16),256,0,stream>>>(xn1_bf+(size_t)cb*1024*H_, W1T+(size_t)4*H2, W1b+4*H_, nullptr,
        nullptr,nullptr,nullptr, t1, 1024, 4*H_, H_);
    k_mfma_nt<0,1,0><<<dim3(8,16),256,0,stream>>>(t1, W2T+(size_t)4*H2, W2b+H_, nullptr,
        out0+(size_t)cb*1024*H_, x_emb_bf+(size_t)cb*1024*H_, nullptr,
        ffy1r_bf+(size_t)cb*1024*H_, 1024, H_, 4*H_);
  }

  // ---- phase B: layer-1 recurrence ----
  PhaseArgs PB{};
  PB.xn_all=xn1_bf; PB.gate_all=g1_bf;
  PB.Wm1T=WmT+4*H2; PB.bm1=Wmb+4*H_;
  PB.Wm2T=WmT+5*H2; PB.bm2=Wmb+5*H_;
  PB.WhT=WhT+(size_t)2*H2; PB.bh1=Whb+H_; PB.bh2=bh+H_;
  PB.h=h1; PB.xcat=xcat; PB.h_all=h1_all; PB.bar=bar;
  k_phase<<<NBLK,256,0,stream>>>(PB);

  // ---- S9: dec = h1_all@Wy1^T + Wyb1 + by1 + ffy1r  (bf16) ----
  k_mfma_nt<0,1,0><<<dim3(8,64),256,0,stream>>>(h1_all, WyT+H2, Wyb+H_, by+H_,
      nullptr, ffy1r_bf, nullptr, dec_bf, BT_, H_, H_);

  // ---- logits: E -> bf16 (overlays dead weight region), then big NT GEMM ----
  k_f2bf_vec<<<2048,256,0,stream>>>(E, E_bf, (V_*H_)/4);
  k_mfma_nt<0,0,1><<<dim3(V_/128, BT_/64),256,0,stream>>>(dec_bf, E_bf, nullptr, nullptr,
      nullptr,nullptr,nullptr, outF, BT_, V_, H_);
}

// Round 4
// 16416.820 us; speedup vs baseline: 6.8841x; 1.0597x over previous
//
#include <hip/hip_runtime.h>
#include <cstdint>
#include <cstring>
#include <cstddef>

#define L_ 2
#define H_ 1024
#define V_ 32000
#define B_ 16
#define T_ 256
#define BT_ 4096
#define EPS_ 1e-6f
#define PBLK 32
#define PTHR 512

typedef __attribute__((ext_vector_type(8))) short bf16x8;
typedef __attribute__((ext_vector_type(4))) short s16x4;
typedef __attribute__((ext_vector_type(4))) float f32x4;
typedef __attribute__((ext_vector_type(4))) int   i32x4;

__device__ __forceinline__ short f2bf(float f){
  uint32_t u; __builtin_memcpy(&u,&f,4);
  u += 0x7fffu + ((u>>16)&1u);
  return (short)(u>>16);
}
__device__ __forceinline__ float bf2f(short s){
  uint32_t u = ((uint32_t)(unsigned short)s)<<16;
  float f; __builtin_memcpy(&f,&u,4); return f;
}

// ---------- coherent (cross-XCD, cache-bypassing) access helpers ----------
// sc0 sc1 loads/stores are served at the coherence point; they neither read
// nor invalidate L1/L2 lines, so cached weights stay resident across stages.
// NOTE gfx950 assembler operand order: `off offset:N sc0 sc1` (offset BEFORE flags).
__device__ __forceinline__ void ld_sc_x8(const void* p, i32x4* d){
  asm volatile(
    "global_load_dwordx4 %0, %8, off sc0 sc1\n\t"
    "global_load_dwordx4 %1, %8, off offset:64 sc0 sc1\n\t"
    "global_load_dwordx4 %2, %8, off offset:128 sc0 sc1\n\t"
    "global_load_dwordx4 %3, %8, off offset:192 sc0 sc1\n\t"
    "global_load_dwordx4 %4, %8, off offset:256 sc0 sc1\n\t"
    "global_load_dwordx4 %5, %8, off offset:320 sc0 sc1\n\t"
    "global_load_dwordx4 %6, %8, off offset:384 sc0 sc1\n\t"
    "global_load_dwordx4 %7, %8, off offset:448 sc0 sc1\n\t"
    "s_waitcnt vmcnt(0)"
    : "=&v"(d[0]),"=&v"(d[1]),"=&v"(d[2]),"=&v"(d[3]),
      "=&v"(d[4]),"=&v"(d[5]),"=&v"(d[6]),"=&v"(d[7])
    : "v"(p) : "memory");
}
__device__ __forceinline__ void ld_sc_x16(const void* p, i32x4* d){
  asm volatile(
    "global_load_dwordx4 %0, %16, off sc0 sc1\n\t"
    "global_load_dwordx4 %1, %16, off offset:64 sc0 sc1\n\t"
    "global_load_dwordx4 %2, %16, off offset:128 sc0 sc1\n\t"
    "global_load_dwordx4 %3, %16, off offset:192 sc0 sc1\n\t"
    "global_load_dwordx4 %4, %16, off offset:256 sc0 sc1\n\t"
    "global_load_dwordx4 %5, %16, off offset:320 sc0 sc1\n\t"
    "global_load_dwordx4 %6, %16, off offset:384 sc0 sc1\n\t"
    "global_load_dwordx4 %7, %16, off offset:448 sc0 sc1\n\t"
    "global_load_dwordx4 %8, %16, off offset:512 sc0 sc1\n\t"
    "global_load_dwordx4 %9, %16, off offset:576 sc0 sc1\n\t"
    "global_load_dwordx4 %10, %16, off offset:640 sc0 sc1\n\t"
    "global_load_dwordx4 %11, %16, off offset:704 sc0 sc1\n\t"
    "global_load_dwordx4 %12, %16, off offset:768 sc0 sc1\n\t"
    "global_load_dwordx4 %13, %16, off offset:832 sc0 sc1\n\t"
    "global_load_dwordx4 %14, %16, off offset:896 sc0 sc1\n\t"
    "global_load_dwordx4 %15, %16, off offset:960 sc0 sc1\n\t"
    "s_waitcnt vmcnt(0)"
    : "=&v"(d[0]),"=&v"(d[1]),"=&v"(d[2]),"=&v"(d[3]),
      "=&v"(d[4]),"=&v"(d[5]),"=&v"(d[6]),"=&v"(d[7]),
      "=&v"(d[8]),"=&v"(d[9]),"=&v"(d[10]),"=&v"(d[11]),
      "=&v"(d[12]),"=&v"(d[13]),"=&v"(d[14]),"=&v"(d[15])
    : "v"(p) : "memory");
}
__device__ __forceinline__ unsigned ld_sc_u16(const void* p){
  unsigned r;
  asm volatile("global_load_ushort %0, %1, off sc0 sc1\n\ts_waitcnt vmcnt(0)"
               : "=&v"(r) : "v"(p) : "memory");
  return r;
}
__device__ __forceinline__ unsigned ld_sc_u32(const void* p){
  unsigned r;
  asm volatile("global_load_dword %0, %1, off sc0 sc1\n\ts_waitcnt vmcnt(0)"
               : "=&v"(r) : "v"(p) : "memory");
  return r;
}
__device__ __forceinline__ void st_sc_u16(void* p, unsigned v){
  asm volatile("global_store_short %0, %1, off sc0 sc1" :: "v"(p), "v"(v) : "memory");
}
__device__ __forceinline__ void st_sc_u32(void* p, unsigned v){
  asm volatile("global_store_dword %0, %1, off sc0 sc1" :: "v"(p), "v"(v) : "memory");
}
__device__ __forceinline__ void drain_vm(){
  asm volatile("s_waitcnt vmcnt(0)" ::: "memory");
}

// ---------------- block reduction over 256 threads ----------------
__device__ __forceinline__ float block_sum256(float v, float* s4){
#pragma unroll
  for(int o=32;o;o>>=1) v += __shfl_down(v,o,64);
  int lane = threadIdx.x & 63, w = threadIdx.x >> 6;
  if(lane==0) s4[w]=v;
  __syncthreads();
  float r = s4[0]+s4[1]+s4[2]+s4[3];
  __syncthreads();
  return r;
}

// ---------------- embedding gather + LayerNorm (layer 0), time-major rows ----------------
__global__ __launch_bounds__(256) void k_embed_ln(
    const float* __restrict__ E, const int* __restrict__ tok,
    const float* __restrict__ g, const float* __restrict__ b,
    short* __restrict__ x_emb_bf, short* __restrict__ xn_bf){
  __shared__ float s4[4];
  int row = blockIdx.x;              // row = t*16 + b
  int t = row >> 4, bb = row & 15;
  int tk = tok[bb*T_ + t];
  float4 v = ((const float4*)(E + (size_t)tk*H_))[threadIdx.x];
  float mean = block_sum256(v.x+v.y+v.z+v.w, s4) * (1.0f/H_);
  float d0=v.x-mean,d1=v.y-mean,d2=v.z-mean,d3=v.w-mean;
  float var = block_sum256(d0*d0+d1*d1+d2*d2+d3*d3, s4) * (1.0f/H_);
  float inv = 1.0f/(sqrtf(var)+EPS_);
  int c = threadIdx.x*4;
  s16x4 eb = {f2bf(v.x),f2bf(v.y),f2bf(v.z),f2bf(v.w)};
  ((s16x4*)(x_emb_bf + (size_t)row*H_))[threadIdx.x] = eb;
  s16x4 ob = {f2bf(g[c+0]*(d0*inv)+b[c+0]), f2bf(g[c+1]*(d1*inv)+b[c+1]),
              f2bf(g[c+2]*(d2*inv)+b[c+2]), f2bf(g[c+3]*(d3*inv)+b[c+3])};
  ((s16x4*)(xn_bf + (size_t)row*H_))[threadIdx.x] = ob;
}

// ---------------- LayerNorm rows f32 -> bf16 ----------------
__global__ __launch_bounds__(256) void k_ln_bf(
    const float* __restrict__ X, const float* __restrict__ g,
    const float* __restrict__ b, short* __restrict__ Y){
  __shared__ float s4[4];
  int row = blockIdx.x;
  float4 v = ((const float4*)(X + (size_t)row*H_))[threadIdx.x];
  float mean = block_sum256(v.x+v.y+v.z+v.w, s4)*(1.0f/H_);
  float d0=v.x-mean,d1=v.y-mean,d2=v.z-mean,d3=v.w-mean;
  float var = block_sum256(d0*d0+d1*d1+d2*d2+d3*d3, s4)*(1.0f/H_);
  float inv = 1.0f/(sqrtf(var)+EPS_);
  int c = threadIdx.x*4;
  s16x4 o = {f2bf(g[c]*(d0*inv)+b[c]), f2bf(g[c+1]*(d1*inv)+b[c+1]),
             f2bf(g[c+2]*(d2*inv)+b[c+2]), f2bf(g[c+3]*(d3*inv)+b[c+3])};
  ((s16x4*)(Y + (size_t)row*H_))[threadIdx.x] = o;
}

// ---------------- transpose fp32 [R,C] -> bf16 [C,R] ----------------
__global__ __launch_bounds__(256) void k_transpose_bf(
    const float* __restrict__ src, short* __restrict__ dst, int Rr, int Cc){
  __shared__ float tile[32][33];
  int c0 = blockIdx.x*32, r0 = blockIdx.y*32;
  int tx = threadIdx.x & 31, ty = threadIdx.x >> 5;
#pragma unroll
  for(int i=0;i<32;i+=8)
    tile[ty+i][tx] = src[(size_t)(r0+ty+i)*Cc + c0+tx];
  __syncthreads();
#pragma unroll
  for(int i=0;i<32;i+=8)
    dst[(size_t)(c0+ty+i)*Rr + r0+tx] = f2bf(tile[tx][ty+i]);
}

// ---------------- fp32 -> bf16 flat convert ----------------
__global__ void k_f2bf_vec(const float* __restrict__ s, short* __restrict__ d, int n4){
  int i = blockIdx.x*blockDim.x + threadIdx.x;
  int st = gridDim.x*blockDim.x;
  for(; i<n4; i+=st){
    float4 v = ((const float4*)s)[i];
    s16x4 o = {f2bf(v.x),f2bf(v.y),f2bf(v.z),f2bf(v.w)};
    ((s16x4*)d)[i] = o;
  }
}

// ---------------- bf16 MFMA NT GEMM, generalized epilogue ----------------
template<int ACT, int OBF, int REMAP>
__global__ __launch_bounds__(256) void k_mfma_nt(
    const short* __restrict__ A, const short* __restrict__ Wt,
    const float* __restrict__ b1, const float* __restrict__ b2,
    const float* __restrict__ rf, const short* __restrict__ rb1,
    const short* __restrict__ rb2, void* __restrict__ out,
    int M, int N, int K){
  int wid = threadIdx.x >> 6, lane = threadIdx.x & 63;
  int m0 = blockIdx.y*64;
  int n0 = blockIdx.x*128 + wid*32;
  int lr = lane & 15, kq = lane >> 4;
  const short* Ap = A + (size_t)(m0+lr)*K + kq*8;
  const short* Bp = Wt + (size_t)(n0+lr)*K + kq*8;
  f32x4 acc[4][2];
#pragma unroll
  for(int i=0;i<4;i++)
#pragma unroll
    for(int j=0;j<2;j++) acc[i][j] = (f32x4)0.0f;
  for(int k=0;k<K;k+=32){
    bf16x8 a[4], b[2];
#pragma unroll
    for(int mi=0;mi<4;mi++) a[mi] = *(const bf16x8*)(Ap + (size_t)mi*16*K + k);
#pragma unroll
    for(int ni=0;ni<2;ni++) b[ni] = *(const bf16x8*)(Bp + (size_t)ni*16*K + k);
#pragma unroll
    for(int mi=0;mi<4;mi++)
#pragma unroll
      for(int ni=0;ni<2;ni++)
        acc[mi][ni] = __builtin_amdgcn_mfma_f32_16x16x32_bf16(a[mi], b[ni], acc[mi][ni], 0,0,0);
  }
#pragma unroll
  for(int mi=0;mi<4;mi++)
#pragma unroll
    for(int ni=0;ni<2;ni++)
#pragma unroll
      for(int r=0;r<4;r++){
        int row = m0 + mi*16 + kq*4 + r;
        int col = n0 + ni*16 + lr;
        float s = acc[mi][ni][r];
        if(b1) s += b1[col];
        if(b2) s += b2[col];
        if(ACT==1) s = 2.0f/(1.0f+expf(-s));
        else if(ACT==2) s = fmaxf(s, 0.0f);
        if(rf)  s += rf[(size_t)row*N+col];
        if(rb1) s += bf2f(rb1[(size_t)row*N+col]);
        if(rb2) s += bf2f(rb2[(size_t)row*N+col]);
        size_t orow = REMAP ? ((size_t)(row&15)*T_ + (row>>4)) : (size_t)row;
        if(OBF) ((short*)out)[orow*N+col] = f2bf(s);
        else    ((float*)out)[orow*N+col] = s;
      }
}

// ---------------- relaxed device barrier: no cache invalidation ----------------
// Data visibility is carried by sc0/sc1 data ops + vmcnt(0) drain, NOT by fences.
__device__ __forceinline__ void gbar(unsigned* bar){
  drain_vm();                 // all my sc-stores visible at coherence point
  __syncthreads();
  if(threadIdx.x==0){
    unsigned gen = ld_sc_u32(bar+1);
    unsigned r = __hip_atomic_fetch_add(bar, 1u, __ATOMIC_RELAXED, __HIP_MEMORY_SCOPE_AGENT);
    if(r == (unsigned)(PBLK-1)){
      __hip_atomic_fetch_sub(bar, (unsigned)PBLK, __ATOMIC_RELAXED, __HIP_MEMORY_SCOPE_AGENT);
      drain_vm();             // reset performed before gen bump becomes visible
      st_sc_u32(bar+1, gen+1u);
    } else {
      while(ld_sc_u32(bar+1)==gen) __builtin_amdgcn_s_sleep(1);
    }
  }
  __syncthreads();
}

// ---------------- persistent recurrence phase kernel ----------------
// 32 blocks x 512 threads; block owns 32 output cols; 8 waves = 2 col-groups x 4 K-splits.
struct PhaseArgs {
  const short* xn_all;   // [T,16,1024] bf16 (cached reads)
  const short* gate_all; // [T,16,1024] bf16 (cached reads)
  const short* Wm1T;     // [1024,1024] (cached, L2-resident)
  const float* bm1;
  const short* Wm2T;
  const float* bm2;
  const short* WhT;      // [1024,2048]
  const float* bh1; const float* bh2;
  short* h;              // [16,1024] bf16 state  (sc access)
  short* xcat;           // [16,2048] bf16        (sc access)
  short* h_all;          // [T,16,1024] bf16      (normal store)
  unsigned* bar;
};

__global__ __launch_bounds__(PTHR,1) void k_phase(PhaseArgs P){
  __shared__ float red[4][2][16][16];
  const int tid = threadIdx.x;
  const int wid = tid>>6, lane = tid&63, lr = lane&15, kq = lane>>4;
  const int ks = wid>>1, cg = wid&1;
  const int n0 = blockIdx.x*32 + cg*16;     // wave's 16 output cols
  const int er = tid>>5, ec = tid&31;       // epilogue row/col-in-block
  const int col = blockIdx.x*32 + ec;
  const int cgE = ec>>4, cE = ec&15;
  for(int t=0;t<T_;t++){
    const short* xn_t = P.xn_all   + (size_t)t*(16*H_);
    const short* g_t  = P.gate_all + (size_t)t*(16*H_);
    // ---- G1: z1 = (h .* g) @ Wm1 ; xcat_lo = xn .* 2sig(z1+b) ----
    {
      i32x4 hv8[8];
      ld_sc_x8(P.h + (size_t)lr*H_ + ks*256 + kq*8, hv8);
      f32x4 acc = (f32x4)0.0f;
#pragma unroll
      for(int kk=0;kk<8;kk++){
        const int k = ks*256 + kq*8 + kk*32;
        bf16x8 h8; __builtin_memcpy(&h8, &hv8[kk], 16);
        bf16x8 g8 = *(const bf16x8*)(g_t + (size_t)lr*H_ + k);
        bf16x8 av;
#pragma unroll
        for(int j=0;j<8;j++) av[j] = f2bf(bf2f(h8[j])*bf2f(g8[j]));
        bf16x8 bv = *(const bf16x8*)(P.Wm1T + (size_t)(n0+lr)*H_ + k);
        acc = __builtin_amdgcn_mfma_f32_16x16x32_bf16(av,bv,acc,0,0,0);
      }
#pragma unroll
      for(int r=0;r<4;r++) red[ks][cg][kq*4+r][lr] = acc[r];
      __syncthreads();
      float s = red[0][cgE][er][cE]+red[1][cgE][er][cE]
              + red[2][cgE][er][cE]+red[3][cgE][er][cE];
      s += P.bm1[col];
      float gate = 2.0f/(1.0f+expf(-s));
      float xv = bf2f(xn_t[(size_t)er*H_ + col]);
      st_sc_u16(P.xcat + (size_t)er*2048 + col,
                (unsigned)(unsigned short)f2bf(xv*gate));
    }
    gbar(P.bar);
    // ---- G2: z2 = xm @ Wm2 ; xcat_hi = (h .* g) .* 2sig(z2+b) ----
    {
      unsigned hraw = ld_sc_u16(P.h + (size_t)er*H_ + col);
      i32x4 av8[8];
      ld_sc_x8(P.xcat + (size_t)lr*2048 + ks*256 + kq*8, av8);
      f32x4 acc = (f32x4)0.0f;
#pragma unroll
      for(int kk=0;kk<8;kk++){
        const int k = ks*256 + kq*8 + kk*32;
        bf16x8 av; __builtin_memcpy(&av, &av8[kk], 16);
        bf16x8 bv = *(const bf16x8*)(P.Wm2T + (size_t)(n0+lr)*H_ + k);
        acc = __builtin_amdgcn_mfma_f32_16x16x32_bf16(av,bv,acc,0,0,0);
      }
#pragma unroll
      for(int r=0;r<4;r++) red[ks][cg][kq*4+r][lr] = acc[r];
      __syncthreads();
      float s = red[0][cgE][er][cE]+red[1][cgE][er][cE]
              + red[2][cgE][er][cE]+red[3][cgE][er][cE];
      s += P.bm2[col];
      float gate = 2.0f/(1.0f+expf(-s));
      float hv = bf2f((short)hraw);
      float gv = bf2f(g_t[(size_t)er*H_ + col]);
      st_sc_u16(P.xcat + (size_t)er*2048 + 1024 + col,
                (unsigned)(unsigned short)f2bf(hv*gv*gate));
    }
    gbar(P.bar);
    // ---- G3: h = tanh([xm,hm] @ Wh + bh1 + bh2)  (K=2048) ----
    {
      i32x4 av16[16];
      ld_sc_x16(P.xcat + (size_t)lr*2048 + ks*512 + kq*8, av16);
      f32x4 acc = (f32x4)0.0f;
#pragma unroll
      for(int kk=0;kk<16;kk++){
        const int k = ks*512 + kq*8 + kk*32;
        bf16x8 av; __builtin_memcpy(&av, &av16[kk], 16);
        bf16x8 bv = *(const bf16x8*)(P.WhT + (size_t)(n0+lr)*2048 + k);
        acc = __builtin_amdgcn_mfma_f32_16x16x32_bf16(av,bv,acc,0,0,0);
      }
#pragma unroll
      for(int r=0;r<4;r++) red[ks][cg][kq*4+r][lr] = acc[r];
      __syncthreads();
      float s = red[0][cgE][er][cE]+red[1][cgE][er][cE]
              + red[2][cgE][er][cE]+red[3][cgE][er][cE];
      s += P.bh1[col] + P.bh2[col];
      short hb = f2bf(tanhf(s));
      st_sc_u16(P.h + (size_t)er*H_ + col, (unsigned)(unsigned short)hb);
      P.h_all[(size_t)t*(16*H_) + (size_t)er*H_ + col] = hb;  // normal store
    }
    gbar(P.bar);
  }
}

extern "C" void kernel_launch(void* const* d_in, const int* in_sizes, int n_in,
                              void* d_out, int out_size, void* d_ws, size_t ws_size,
                              hipStream_t stream){
  const float* E    = (const float*)d_in[0];
  const float* ln_g = (const float*)d_in[1];
  const float* ln_b = (const float*)d_in[2];
  const float* Wm   = (const float*)d_in[3];   // [2,3,H,H]
  const float* Wmb  = (const float*)d_in[4];   // [2,3,H]
  const float* Wh   = (const float*)d_in[5];   // [2,2H,H]
  const float* Whb  = (const float*)d_in[6];
  const float* bh   = (const float*)d_in[7];
  const float* Wy   = (const float*)d_in[8];   // [2,H,H]
  const float* Wyb  = (const float*)d_in[9];
  const float* by   = (const float*)d_in[10];
  const float* W1   = (const float*)d_in[11];  // [2,H,4H]
  const float* W1b  = (const float*)d_in[12];  // [2,4H]
  const float* W2   = (const float*)d_in[13];  // [2,4H,H]
  const float* W2b  = (const float*)d_in[14];
  const int*   xx   = (const int*)d_in[15];
  float* outF = (float*)d_out;
  (void)in_sizes; (void)n_in; (void)out_size; (void)ws_size;

  const size_t H2 = (size_t)H_*H_;
  char* p = (char*)d_ws;
  auto alloc = [&](size_t bytes)->void*{ void* r=(void*)p; p += (bytes+255)&~(size_t)255; return r; };

  // persistent region
  short* x_emb_bf = (short*)alloc((size_t)BT_*H_*2);
  short* xn0_bf   = (short*)alloc((size_t)BT_*H_*2);
  short* mg0_bf   = (short*)alloc((size_t)BT_*H_*2);
  short* ff0_bf   = (short*)alloc((size_t)BT_*H_*2);
  float* out0     = (float*)alloc((size_t)BT_*H_*4);
  short* xn1_bf   = (short*)alloc((size_t)BT_*H_*2);
  short* g1_bf    = (short*)alloc((size_t)BT_*H_*2);
  short* ffy1r_bf = (short*)alloc((size_t)BT_*H_*2);
  short* h0_all   = (short*)alloc((size_t)BT_*H_*2);
  short* h1_all   = (short*)alloc((size_t)BT_*H_*2);
  short* dec_bf   = (short*)alloc((size_t)BT_*H_*2);
  // zero-init region (contiguous): h0, h1, xcat, bar
  char*  z0   = p;
  short* h0   = (short*)alloc((size_t)16*H_*2);
  short* h1   = (short*)alloc((size_t)16*H_*2);
  short* xcat = (short*)alloc((size_t)16*2*H_*2);
  unsigned* bar = (unsigned*)alloc(256);
  size_t zbytes = (size_t)(p - z0);
  // weight region (dead after S9) — E_bf overlays it at the end
  char*  wreg = p;
  short* WmT = (short*)alloc(6*H2*2);              // [6][1024][1024]
  short* WhT = (short*)alloc(2*(size_t)H_*2*H_*2); // [2][1024][2048]
  short* WyT = (short*)alloc(2*H2*2);
  short* W1T = (short*)alloc(2*(size_t)4*H_*H_*2); // [2][4096][1024]
  short* W2T = (short*)alloc(2*(size_t)H_*4*H_*2); // [2][1024][4096]
  short* t1  = (short*)alloc((size_t)1024*4*H_*2); // FFN chunk buffer
  short* E_bf = (short*)wreg;                      // overlay: 62.5MB <= 64MB region

  hipMemsetAsync(z0, 0, zbytes, stream);

  // ---- precompute ----
  k_embed_ln<<<BT_,256,0,stream>>>(E, xx, ln_g, ln_b, x_emb_bf, xn0_bf);
  for(int i=0;i<6;i++)
    k_transpose_bf<<<dim3(32,32),256,0,stream>>>(Wm+i*H2, WmT+i*H2, H_, H_);
  for(int l=0;l<2;l++){
    k_transpose_bf<<<dim3(32,64),256,0,stream>>>(Wh+(size_t)l*2*H2, WhT+(size_t)l*2*H2, 2*H_, H_);
    k_transpose_bf<<<dim3(32,32),256,0,stream>>>(Wy+(size_t)l*H2, WyT+(size_t)l*H2, H_, H_);
    k_transpose_bf<<<dim3(128,32),256,0,stream>>>(W1+(size_t)l*4*H2, W1T+(size_t)l*4*H2, H_, 4*H_);
    k_transpose_bf<<<dim3(32,128),256,0,stream>>>(W2+(size_t)l*4*H2, W2T+(size_t)l*4*H2, 4*H_, H_);
  }
  // mg0 = 2sig(xn0 @ Wm[0,0]^T + b)
  k_mfma_nt<1,1,0><<<dim3(8,64),256,0,stream>>>(xn0_bf, WmT, Wmb, nullptr,
      nullptr,nullptr,nullptr, mg0_bf, BT_, H_, H_);
  // layer-0 FFN (chunked): ff0 = relu(xn0@W1_0+b)@W2_0 + b
  for(int cb=0;cb<4;cb++){
    k_mfma_nt<2,1,0><<<dim3(32,16),256,0,stream>>>(xn0_bf+(size_t)cb*1024*H_, W1T, W1b, nullptr,
        nullptr,nullptr,nullptr, t1, 1024, 4*H_, H_);
    k_mfma_nt<0,1,0><<<dim3(8,16),256,0,stream>>>(t1, W2T, W2b, nullptr,
        nullptr,nullptr,nullptr, ff0_bf+(size_t)cb*1024*H_, 1024, H_, 4*H_);
  }

  // ---- phase A: layer-0 recurrence ----
  PhaseArgs PA{};
  PA.xn_all=xn0_bf; PA.gate_all=mg0_bf;
  PA.Wm1T=WmT+1*H2; PA.bm1=Wmb+1*H_;
  PA.Wm2T=WmT+2*H2; PA.bm2=Wmb+2*H_;
  PA.WhT=WhT; PA.bh1=Whb; PA.bh2=bh;
  PA.h=h0; PA.xcat=xcat; PA.h_all=h0_all; PA.bar=bar;
  k_phase<<<PBLK,PTHR,0,stream>>>(PA);

  // ---- batched middle ----
  k_mfma_nt<0,0,0><<<dim3(8,64),256,0,stream>>>(h0_all, WyT, Wyb, by,
      nullptr, x_emb_bf, ff0_bf, out0, BT_, H_, H_);
  k_ln_bf<<<BT_,256,0,stream>>>(out0, ln_g+H_, ln_b+H_, xn1_bf);
  k_mfma_nt<1,1,0><<<dim3(8,64),256,0,stream>>>(xn1_bf, WmT+3*H2, Wmb+3*H_, nullptr,
      nullptr,nullptr,nullptr, g1_bf, BT_, H_, H_);
  for(int cb=0;cb<4;cb++){
    k_mfma_nt<2,1,0><<<dim3(32,16),256,0,stream>>>(xn1_bf+(size_t)cb*1024*H_, W1T+(size_t)4*H2, W1b+4*H_, nullptr,
        nullptr,nullptr,nullptr, t1, 1024, 4*H_, H_);
    k_mfma_nt<0,1,0><<<dim3(8,16),256,0,stream>>>(t1, W2T+(size_t)4*H2, W2b+H_, nullptr,
        out0+(size_t)cb*1024*H_, x_emb_bf+(size_t)cb*1024*H_, nullptr,
        ffy1r_bf+(size_t)cb*1024*H_, 1024, H_, 4*H_);
  }

  // ---- phase B: layer-1 recurrence ----
  PhaseArgs PB{};
  PB.xn_all=xn1_bf; PB.gate_all=g1_bf;
  PB.Wm1T=WmT+4*H2; PB.bm1=Wmb+4*H_;
  PB.Wm2T=WmT+5*H2; PB.bm2=Wmb+5*H_;
  PB.WhT=WhT+(size_t)2*H2; PB.bh1=Whb+H_; PB.bh2=bh+H_;
  PB.h=h1; PB.xcat=xcat; PB.h_all=h1_all; PB.bar=bar;
  k_phase<<<PBLK,PTHR,0,stream>>>(PB);

  // ---- S9: dec = h1_all@Wy1^T + Wyb1 + by1 + ffy1r  (bf16) ----
  k_mfma_nt<0,1,0><<<dim3(8,64),256,0,stream>>>(h1_all, WyT+H2, Wyb+H_, by+H_,
      nullptr, ffy1r_bf, nullptr, dec_bf, BT_, H_, H_);

  // ---- logits: E -> bf16 (overlays dead weight region), then big NT GEMM ----
  k_f2bf_vec<<<2048,256,0,stream>>>(E, E_bf, (V_*H_)/4);
  k_mfma_nt<0,0,1><<<dim3(V_/128, BT_/64),256,0,stream>>>(dec_bf, E_bf, nullptr, nullptr,
      nullptr,nullptr,nullptr, outF, BT_, V_, H_);
}

// Round 5
// 9619.114 us; speedup vs baseline: 11.7490x; 1.7067x over previous
//
#include <hip/hip_runtime.h>
#include <cstdint>
#include <cstring>
#include <cstddef>

#define L_ 2
#define H_ 1024
#define V_ 32000
#define B_ 16
#define T_ 256
#define BT_ 4096
#define EPS_ 1e-6f

typedef __attribute__((ext_vector_type(8))) short bf16x8;
typedef __attribute__((ext_vector_type(4))) short s16x4;
typedef __attribute__((ext_vector_type(4))) float f32x4;
typedef __attribute__((ext_vector_type(4))) int   i32x4;

__device__ __forceinline__ short f2bf(float f){
  uint32_t u; __builtin_memcpy(&u,&f,4);
  u += 0x7fffu + ((u>>16)&1u);
  return (short)(u>>16);
}
__device__ __forceinline__ float bf2f(short s){
  uint32_t u = ((uint32_t)(unsigned short)s)<<16;
  float f; __builtin_memcpy(&f,&u,4); return f;
}
__device__ __forceinline__ unsigned pack2(short a, short b){
  return (unsigned)(unsigned short)a | ((unsigned)(unsigned short)b << 16);
}

// ---------- coherent (cross-XCD, cache-bypassing) access helpers ----------
__device__ __forceinline__ void ld_sc_x4v(const void* p, i32x4* d){
  asm volatile(
    "global_load_dwordx4 %0, %4, off sc0 sc1\n\t"
    "global_load_dwordx4 %1, %4, off offset:16 sc0 sc1\n\t"
    "global_load_dwordx4 %2, %4, off offset:32 sc0 sc1\n\t"
    "global_load_dwordx4 %3, %4, off offset:48 sc0 sc1\n\t"
    "s_waitcnt vmcnt(0)"
    : "=&v"(d[0]),"=&v"(d[1]),"=&v"(d[2]),"=&v"(d[3])
    : "v"(p) : "memory");
}
__device__ __forceinline__ unsigned ld_sc_u32(const void* p){
  unsigned r;
  asm volatile("global_load_dword %0, %1, off sc0 sc1\n\ts_waitcnt vmcnt(0)"
               : "=&v"(r) : "v"(p) : "memory");
  return r;
}
__device__ __forceinline__ void st_sc_u32(void* p, unsigned v){
  asm volatile("global_store_dword %0, %1, off sc0 sc1" :: "v"(p), "v"(v) : "memory");
}
__device__ __forceinline__ void st_sc_x4(void* p, i32x4 v){
  asm volatile("global_store_dwordx4 %0, %1, off sc0 sc1" :: "v"(p), "v"(v) : "memory");
}
__device__ __forceinline__ void drain_vm(){
  asm volatile("s_waitcnt vmcnt(0)" ::: "memory");
}

// ---------- one-sided flag waits (monotonic, write-once per launch) ----------
__device__ __forceinline__ void wait_flags16(const unsigned* f){
  if(threadIdx.x < 64){
    const unsigned* p = f + (threadIdx.x & 15);
    while(ld_sc_u32(p)==0u) __builtin_amdgcn_s_sleep(1);
  }
  __syncthreads();
}
__device__ __forceinline__ void wait_flag1(const unsigned* f){
  if(threadIdx.x < 64){
    while(ld_sc_u32(f)==0u) __builtin_amdgcn_s_sleep(1);
  }
  __syncthreads();
}

// ---------------- block reduction over 256 threads ----------------
__device__ __forceinline__ float block_sum256(float v, float* s4){
#pragma unroll
  for(int o=32;o;o>>=1) v += __shfl_down(v,o,64);
  int lane = threadIdx.x & 63, w = threadIdx.x >> 6;
  if(lane==0) s4[w]=v;
  __syncthreads();
  float r = s4[0]+s4[1]+s4[2]+s4[3];
  __syncthreads();
  return r;
}

// ---------------- embedding gather + LayerNorm (layer 0), time-major rows ----------------
__global__ __launch_bounds__(256) void k_embed_ln(
    const float* __restrict__ E, const int* __restrict__ tok,
    const float* __restrict__ g, const float* __restrict__ b,
    short* __restrict__ x_emb_bf, short* __restrict__ xn_bf){
  __shared__ float s4[4];
  int row = blockIdx.x;              // row = t*16 + b
  int t = row >> 4, bb = row & 15;
  int tk = tok[bb*T_ + t];
  float4 v = ((const float4*)(E + (size_t)tk*H_))[threadIdx.x];
  float mean = block_sum256(v.x+v.y+v.z+v.w, s4) * (1.0f/H_);
  float d0=v.x-mean,d1=v.y-mean,d2=v.z-mean,d3=v.w-mean;
  float var = block_sum256(d0*d0+d1*d1+d2*d2+d3*d3, s4) * (1.0f/H_);
  float inv = 1.0f/(sqrtf(var)+EPS_);
  int c = threadIdx.x*4;
  s16x4 eb = {f2bf(v.x),f2bf(v.y),f2bf(v.z),f2bf(v.w)};
  ((s16x4*)(x_emb_bf + (size_t)row*H_))[threadIdx.x] = eb;
  s16x4 ob = {f2bf(g[c+0]*(d0*inv)+b[c+0]), f2bf(g[c+1]*(d1*inv)+b[c+1]),
              f2bf(g[c+2]*(d2*inv)+b[c+2]), f2bf(g[c+3]*(d3*inv)+b[c+3])};
  ((s16x4*)(xn_bf + (size_t)row*H_))[threadIdx.x] = ob;
}

// ---------------- transpose fp32 [R,C] -> bf16 [C,R] ----------------
__global__ __launch_bounds__(256) void k_transpose_bf(
    const float* __restrict__ src, short* __restrict__ dst, int Rr, int Cc){
  __shared__ float tile[32][33];
  int c0 = blockIdx.x*32, r0 = blockIdx.y*32;
  int tx = threadIdx.x & 31, ty = threadIdx.x >> 5;
#pragma unroll
  for(int i=0;i<32;i+=8)
    tile[ty+i][tx] = src[(size_t)(r0+ty+i)*Cc + c0+tx];
  __syncthreads();
#pragma unroll
  for(int i=0;i<32;i+=8)
    dst[(size_t)(c0+ty+i)*Rr + r0+tx] = f2bf(tile[tx][ty+i]);
}

// ---------------- fp32 -> bf16 flat convert ----------------
__global__ void k_f2bf_vec(const float* __restrict__ s, short* __restrict__ d, int n4){
  int i = blockIdx.x*blockDim.x + threadIdx.x;
  int st = gridDim.x*blockDim.x;
  for(; i<n4; i+=st){
    float4 v = ((const float4*)s)[i];
    s16x4 o = {f2bf(v.x),f2bf(v.y),f2bf(v.z),f2bf(v.w)};
    ((s16x4*)d)[i] = o;
  }
}

// ---------------- bf16 MFMA NT GEMM, generalized epilogue ----------------
template<int ACT, int OBF, int REMAP>
__global__ __launch_bounds__(256) void k_mfma_nt(
    const short* __restrict__ A, const short* __restrict__ Wt,
    const float* __restrict__ b1, const float* __restrict__ b2,
    const float* __restrict__ rf, const short* __restrict__ rb1,
    const short* __restrict__ rb2, void* __restrict__ out,
    int M, int N, int K){
  int wid = threadIdx.x >> 6, lane = threadIdx.x & 63;
  int m0 = blockIdx.y*64;
  int n0 = blockIdx.x*128 + wid*32;
  int lr = lane & 15, kq = lane >> 4;
  const short* Ap = A + (size_t)(m0+lr)*K + kq*8;
  const short* Bp = Wt + (size_t)(n0+lr)*K + kq*8;
  f32x4 acc[4][2];
#pragma unroll
  for(int i=0;i<4;i++)
#pragma unroll
    for(int j=0;j<2;j++) acc[i][j] = (f32x4)0.0f;
  for(int k=0;k<K;k+=32){
    bf16x8 a[4], b[2];
#pragma unroll
    for(int mi=0;mi<4;mi++) a[mi] = *(const bf16x8*)(Ap + (size_t)mi*16*K + k);
#pragma unroll
    for(int ni=0;ni<2;ni++) b[ni] = *(const bf16x8*)(Bp + (size_t)ni*16*K + k);
#pragma unroll
    for(int mi=0;mi<4;mi++)
#pragma unroll
      for(int ni=0;ni<2;ni++)
        acc[mi][ni] = __builtin_amdgcn_mfma_f32_16x16x32_bf16(a[mi], b[ni], acc[mi][ni], 0,0,0);
  }
#pragma unroll
  for(int mi=0;mi<4;mi++)
#pragma unroll
    for(int ni=0;ni<2;ni++)
#pragma unroll
      for(int r=0;r<4;r++){
        int row = m0 + mi*16 + kq*4 + r;
        int col = n0 + ni*16 + lr;
        float s = acc[mi][ni][r];
        if(b1) s += b1[col];
        if(b2) s += b2[col];
        if(ACT==1) s = 2.0f/(1.0f+expf(-s));
        else if(ACT==2) s = fmaxf(s, 0.0f);
        if(rf)  s += rf[(size_t)row*N+col];
        if(rb1) s += bf2f(rb1[(size_t)row*N+col]);
        if(rb2) s += bf2f(rb2[(size_t)row*N+col]);
        size_t orow = REMAP ? ((size_t)(row&15)*T_ + (row>>4)) : (size_t)row;
        if(OBF) ((short*)out)[orow*N+col] = f2bf(s);
        else    ((float*)out)[orow*N+col] = s;
      }
}

// ================= persistent pipelined megakernel =================
struct MegaArgs {
  const short *xn0, *mg0;      // [T][16][1024] precomputed, cached
  const short *WmT;            // [6][H][H]
  const float *Wmb;            // [6][H]
  const short *WhT;            // [2][H][2H]
  const float *Whb, *bh;       // [2][H]
  const short *WyT;            // [2][H][H]
  const float *Wyb, *by;
  const short *xemb, *ff0;     // [T*16][1024] bf16
  const float *lng, *lnb;      // layer-1 LN params
  float *out0;                 // [T*16][1024] f32 (normal stores; post-kernel + LN readback)
  short *xn1, *g1;             // sc (intra-kernel consumers)
  short *h0, *h1;              // [16][1024] states (sc)
  short *xcat0, *xcat1;        // [16][2048] (sc)
  short *h0_all, *h1_all;      // [T][16][1024] (sc)
  unsigned *fA0,*fB0,*fC0,*fA1,*fB1,*fC1,*dM;
};

struct RArgs {
  const short *xn, *gate, *Wm1T, *Wm2T, *WhT;
  const float *bm1, *bm2, *bh1, *bh2;
  short *h, *xcat, *h_all;
  unsigned *fA, *fB, *fC; const unsigned* dM;
};

#define RED(buf, ksv, c, re) buf[((((ksv)*4)+((c)>>4))*16 + (re))*16 + ((c)&15)]
#define SWI(row,e) ((e) ^ (((row)&7)<<3))

// recurrence group: 16 blocks, block owns 64 output cols; 8 waves = 4 colgrp x 2 Ksplit
template<int SC>
__device__ void recur_group(const RArgs& A, int blk, char* smem){
  short* x2   = (short*)smem;            // [16][1024] bf16, XOR-swizzled stash
  float* red1 = (float*)(smem + 32768);  // [2][4][16][16]
  float* red3 = (float*)(smem + 40960);
  const int tid=threadIdx.x, w=tid>>6, lane=tid&63, lr=lane&15, kq=lane>>4;
  const int cg=w&3, ks=w>>2;
  const int wcol = blk*64 + cg*16;
  const int re = tid>>5, cp = tid&31, c0 = cp*2, c1 = c0+1, gc0 = blk*64 + c0;
  const int rl = tid>>5, seg = tid&31;
  float p3_0=0.f, p3_1=0.f;

  for(int t=0;t<T_;++t){
    const short* xn_t = A.xn + (size_t)t*16384;
    const short* g_t  = A.gate + (size_t)t*16384;
    // ======== stage A: xm = xn .* 2sig((h.*g)@Wm1 + b) ========
    if(SC) wait_flag1(A.dM + t);
    if(t)  wait_flags16(A.fC + (size_t)(t-1)*16);
    {
      i32x4 hv[4], gv[4];
      ld_sc_x4v(A.h + (size_t)rl*1024 + seg*32, hv);
      if(SC) ld_sc_x4v(g_t + (size_t)rl*1024 + seg*32, gv);
      else { const i32x4* gp = (const i32x4*)(g_t + (size_t)rl*1024 + seg*32);
             gv[0]=gp[0]; gv[1]=gp[1]; gv[2]=gp[2]; gv[3]=gp[3]; }
#pragma unroll
      for(int u=0;u<4;u++){
        bf16x8 h8,g8,pr;
        __builtin_memcpy(&h8,&hv[u],16); __builtin_memcpy(&g8,&gv[u],16);
#pragma unroll
        for(int j=0;j<8;j++) pr[j] = f2bf(bf2f(h8[j])*bf2f(g8[j]));
        int e = seg*32+u*8;
        *(bf16x8*)(x2 + (size_t)rl*1024 + SWI(rl,e)) = pr;
      }
    }
    __syncthreads();
    {
      f32x4 acc = (f32x4)0.0f;
#pragma unroll
      for(int kk=0;kk<16;kk++){
        int k = ks*512 + kk*32 + kq*8;
        bf16x8 a = *(const bf16x8*)(x2 + (size_t)lr*1024 + SWI(lr,k));
        bf16x8 b = *(const bf16x8*)(A.Wm1T + (size_t)(wcol+lr)*1024 + k);
        acc = __builtin_amdgcn_mfma_f32_16x16x32_bf16(a,b,acc,0,0,0);
      }
#pragma unroll
      for(int r=0;r<4;r++) RED(red1,ks,cg*16+lr,kq*4+r) = acc[r];
    }
    __syncthreads();
    {
      float z0 = RED(red1,0,c0,re) + RED(red1,1,c0,re);
      float z1 = RED(red1,0,c1,re) + RED(red1,1,c1,re);
      float ga0 = 2.f/(1.f+expf(-(z0 + A.bm1[gc0])));
      float ga1 = 2.f/(1.f+expf(-(z1 + A.bm1[gc0+1])));
      unsigned xp;
      if(SC) xp = ld_sc_u32(xn_t + (size_t)re*1024 + gc0);
      else   xp = *(const unsigned*)(xn_t + (size_t)re*1024 + gc0);
      float x0 = bf2f((short)(xp&0xffff)), x1 = bf2f((short)(xp>>16));
      st_sc_u32(A.xcat + (size_t)re*2048 + gc0, pack2(f2bf(x0*ga0), f2bf(x1*ga1)));
    }
    drain_vm(); __syncthreads();
    if(tid==0) st_sc_u32(A.fA + (size_t)t*16 + blk, 1u);
    wait_flags16(A.fA + (size_t)t*16);
    // ======== stage B: hm = (h.*g) .* 2sig(xm@Wm2 + b); p3 = xm@Wh_top ========
    unsigned hp = ld_sc_u32(A.h + (size_t)re*1024 + gc0);
    unsigned gp2;
    if(SC) gp2 = ld_sc_u32(g_t + (size_t)re*1024 + gc0);
    else   gp2 = *(const unsigned*)(g_t + (size_t)re*1024 + gc0);
    {
      i32x4 xv[4]; ld_sc_x4v(A.xcat + (size_t)rl*2048 + seg*32, xv);
#pragma unroll
      for(int u=0;u<4;u++)
        *(i32x4*)(x2 + (size_t)rl*1024 + SWI(rl,seg*32+u*8)) = xv[u];
    }
    __syncthreads();
    {
      f32x4 acc2=(f32x4)0.0f, acc3=(f32x4)0.0f;
#pragma unroll
      for(int kk=0;kk<16;kk++){
        int k = ks*512 + kk*32 + kq*8;
        bf16x8 a  = *(const bf16x8*)(x2 + (size_t)lr*1024 + SWI(lr,k));
        bf16x8 b2 = *(const bf16x8*)(A.Wm2T + (size_t)(wcol+lr)*1024 + k);
        bf16x8 b3 = *(const bf16x8*)(A.WhT  + (size_t)(wcol+lr)*2048 + k);
        acc2 = __builtin_amdgcn_mfma_f32_16x16x32_bf16(a,b2,acc2,0,0,0);
        acc3 = __builtin_amdgcn_mfma_f32_16x16x32_bf16(a,b3,acc3,0,0,0);
      }
#pragma unroll
      for(int r=0;r<4;r++){
        RED(red1,ks,cg*16+lr,kq*4+r) = acc2[r];
        RED(red3,ks,cg*16+lr,kq*4+r) = acc3[r];
      }
    }
    __syncthreads();
    {
      float z0 = RED(red1,0,c0,re) + RED(red1,1,c0,re);
      float z1 = RED(red1,0,c1,re) + RED(red1,1,c1,re);
      p3_0 = RED(red3,0,c0,re) + RED(red3,1,c0,re);
      p3_1 = RED(red3,0,c1,re) + RED(red3,1,c1,re);
      float ga0 = 2.f/(1.f+expf(-(z0 + A.bm2[gc0])));
      float ga1 = 2.f/(1.f+expf(-(z1 + A.bm2[gc0+1])));
      float hv0 = bf2f((short)(hp&0xffff)) * bf2f((short)(gp2&0xffff)) * ga0;
      float hv1 = bf2f((short)(hp>>16))    * bf2f((short)(gp2>>16))    * ga1;
      st_sc_u32(A.xcat + (size_t)re*2048 + 1024 + gc0, pack2(f2bf(hv0), f2bf(hv1)));
    }
    drain_vm(); __syncthreads();
    if(tid==0) st_sc_u32(A.fB + (size_t)t*16 + blk, 1u);
    wait_flags16(A.fB + (size_t)t*16);
    // ======== stage C: h' = tanh(p3 + hm@Wh_bot + bh1 + bh2) ========
    {
      i32x4 xv[4]; ld_sc_x4v(A.xcat + (size_t)rl*2048 + 1024 + seg*32, xv);
#pragma unroll
      for(int u=0;u<4;u++)
        *(i32x4*)(x2 + (size_t)rl*1024 + SWI(rl,seg*32+u*8)) = xv[u];
    }
    __syncthreads();
    {
      f32x4 acc = (f32x4)0.0f;
#pragma unroll
      for(int kk=0;kk<16;kk++){
        int k = ks*512 + kk*32 + kq*8;
        bf16x8 a = *(const bf16x8*)(x2 + (size_t)lr*1024 + SWI(lr,k));
        bf16x8 b = *(const bf16x8*)(A.WhT + (size_t)(wcol+lr)*2048 + 1024 + k);
        acc = __builtin_amdgcn_mfma_f32_16x16x32_bf16(a,b,acc,0,0,0);
      }
#pragma unroll
      for(int r=0;r<4;r++) RED(red1,ks,cg*16+lr,kq*4+r) = acc[r];
    }
    __syncthreads();
    {
      float z0 = RED(red1,0,c0,re) + RED(red1,1,c0,re) + p3_0 + A.bh1[gc0]   + A.bh2[gc0];
      float z1 = RED(red1,0,c1,re) + RED(red1,1,c1,re) + p3_1 + A.bh1[gc0+1] + A.bh2[gc0+1];
      unsigned pk = pack2(f2bf(tanhf(z0)), f2bf(tanhf(z1)));
      st_sc_u32(A.h + (size_t)re*1024 + gc0, pk);
      st_sc_u32(A.h_all + (size_t)t*16384 + (size_t)re*1024 + gc0, pk);
    }
    drain_vm(); __syncthreads();
    if(tid==0) st_sc_u32(A.fC + (size_t)t*16 + blk, 1u);
  }
}

// middle group: 32 blocks, block m handles t = m, m+32, ... fully locally (no barriers)
__device__ void middle_group(const MegaArgs& M, int m, char* smem){
  short* stash   = (short*)smem;            // [16][1024] bf16 swizzled (A operand)
  short* staging = (short*)(smem + 32768);  // [16][1024] bf16 (g1 pack)
  const size_t H2 = (size_t)H_*H_;
  const short* WgT = M.WmT + 3*H2;
  const float* bm0 = M.Wmb + 3*H_;
  const int tid=threadIdx.x, w=tid>>6, lane=tid&63, lr=lane&15, kq=lane>>4;
  const int rl=tid>>5, seg=tid&31;
  const int wc = w*128;
  for(int t=m; t<T_; t+=32){
    wait_flags16(M.fC0 + (size_t)t*16);
    { // stash h0[t]
      i32x4 hv[4]; ld_sc_x4v(M.h0_all + (size_t)t*16384 + (size_t)rl*1024 + seg*32, hv);
#pragma unroll
      for(int u=0;u<4;u++)
        *(i32x4*)(stash + (size_t)rl*1024 + SWI(rl,seg*32+u*8)) = hv[u];
    }
    __syncthreads();
    { // GEMM1: out0 = h0@Wy0 + wyb + by + x_emb + ff0  (normal f32 stores)
      f32x4 acc[8];
#pragma unroll
      for(int n=0;n<8;n++) acc[n]=(f32x4)0.0f;
      for(int kk=0;kk<32;kk++){
        int k = kk*32 + kq*8;
        bf16x8 a = *(const bf16x8*)(stash + (size_t)lr*1024 + SWI(lr,k));
#pragma unroll
        for(int n=0;n<8;n++){
          bf16x8 b = *(const bf16x8*)(M.WyT + (size_t)(wc+n*16+lr)*1024 + k);
          acc[n] = __builtin_amdgcn_mfma_f32_16x16x32_bf16(a,b,acc[n],0,0,0);
        }
      }
#pragma unroll
      for(int n=0;n<8;n++)
#pragma unroll
        for(int r=0;r<4;r++){
          int row = kq*4+r, col = wc+n*16+lr;
          size_t gi = (size_t)t*16384 + (size_t)row*1024 + col;
          M.out0[gi] = acc[n][r] + M.Wyb[col] + M.by[col]
                     + bf2f(M.xemb[gi]) + bf2f(M.ff0[gi]);
        }
    }
    drain_vm(); __syncthreads();
    // LN: wave handles rows 2w, 2w+1 (reads back own block's out0 via L2)
#pragma unroll
    for(int rr=0; rr<2; rr++){
      int row = w*2+rr;
      const float* orow = M.out0 + (size_t)t*16384 + (size_t)row*1024;
      float pv[16];
#pragma unroll
      for(int i2=0;i2<4;i2++){
        float4 v4 = *(const float4*)(orow + lane*16 + i2*4);
        pv[i2*4+0]=v4.x; pv[i2*4+1]=v4.y; pv[i2*4+2]=v4.z; pv[i2*4+3]=v4.w;
      }
      float s=0.f,q=0.f;
#pragma unroll
      for(int i=0;i<16;i++){ s += pv[i]; q += pv[i]*pv[i]; }
#pragma unroll
      for(int o=32;o;o>>=1){ s += __shfl_down(s,o,64); q += __shfl_down(q,o,64); }
      s = __shfl(s,0,64); q = __shfl(q,0,64);
      float mu = s*(1.f/1024.f);
      float sg = sqrtf(fmaxf(q*(1.f/1024.f) - mu*mu, 0.f));
      float inv = 1.f/(sg + EPS_);
      short xb[16];
#pragma unroll
      for(int i=0;i<16;i++){
        int c = lane*16+i;
        xb[i] = f2bf(M.lng[c]*((pv[i]-mu)*inv) + M.lnb[c]);
      }
      i32x4 v0, v1;
#pragma unroll
      for(int j=0;j<4;j++){
        v0[j] = (int)pack2(xb[2*j],   xb[2*j+1]);
        v1[j] = (int)pack2(xb[8+2*j], xb[9+2*j]);
      }
      short* xrow = M.xn1 + (size_t)t*16384 + (size_t)row*1024;
      st_sc_x4(xrow + lane*16, v0);
      st_sc_x4(xrow + lane*16 + 8, v1);
      *(i32x4*)(stash + (size_t)row*1024 + SWI(row,lane*16))   = v0;
      *(i32x4*)(stash + (size_t)row*1024 + SWI(row,lane*16+8)) = v1;
    }
    __syncthreads();
    { // GEMM2: g1 = 2sig(xn1@Wm[1,0] + b)
      f32x4 acg[8];
#pragma unroll
      for(int n=0;n<8;n++) acg[n]=(f32x4)0.0f;
      for(int kk=0;kk<32;kk++){
        int k = kk*32 + kq*8;
        bf16x8 a = *(const bf16x8*)(stash + (size_t)lr*1024 + SWI(lr,k));
#pragma unroll
        for(int n=0;n<8;n++){
          bf16x8 b = *(const bf16x8*)(WgT + (size_t)(wc+n*16+lr)*1024 + k);
          acg[n] = __builtin_amdgcn_mfma_f32_16x16x32_bf16(a,b,acg[n],0,0,0);
        }
      }
#pragma unroll
      for(int n=0;n<8;n++)
#pragma unroll
        for(int r=0;r<4;r++){
          int row = kq*4+r, col = wc+n*16+lr;
          float gte = 2.f/(1.f+expf(-(acg[n][r] + bm0[col])));
          staging[(size_t)row*1024 + col] = f2bf(gte);
        }
    }
    __syncthreads();
    {
      short* grow = M.g1 + (size_t)t*16384 + (size_t)rl*1024 + seg*32;
#pragma unroll
      for(int u=0;u<4;u++){
        i32x4 g4 = *(const i32x4*)(staging + (size_t)rl*1024 + seg*32 + u*8);
        st_sc_x4(grow + u*8, g4);
      }
    }
    drain_vm(); __syncthreads();
    if(tid==0) st_sc_u32(M.dM + t, 1u);
  }
}

__global__ __launch_bounds__(512,1) void k_mega(MegaArgs M){
  __shared__ char smem[65536];
  const size_t H2 = (size_t)H_*H_;
  int b = blockIdx.x;
  if(b < 16){
    RArgs R{M.xn0, M.mg0, M.WmT+1*H2, M.WmT+2*H2, M.WhT,
            M.Wmb+1*H_, M.Wmb+2*H_, M.Whb, M.bh,
            M.h0, M.xcat0, M.h0_all, M.fA0, M.fB0, M.fC0, nullptr};
    recur_group<0>(R, b, smem);
  } else if(b < 48){
    middle_group(M, b-16, smem);
  } else {
    RArgs R{M.xn1, M.g1, M.WmT+4*H2, M.WmT+5*H2, M.WhT+2*H2,
            M.Wmb+4*H_, M.Wmb+5*H_, M.Whb+H_, M.bh+H_,
            M.h1, M.xcat1, M.h1_all, M.fA1, M.fB1, M.fC1, M.dM};
    recur_group<1>(R, b-48, smem);
  }
}

extern "C" void kernel_launch(void* const* d_in, const int* in_sizes, int n_in,
                              void* d_out, int out_size, void* d_ws, size_t ws_size,
                              hipStream_t stream){
  const float* E    = (const float*)d_in[0];
  const float* ln_g = (const float*)d_in[1];
  const float* ln_b = (const float*)d_in[2];
  const float* Wm   = (const float*)d_in[3];   // [2,3,H,H]
  const float* Wmb  = (const float*)d_in[4];   // [2,3,H]
  const float* Wh   = (const float*)d_in[5];   // [2,2H,H]
  const float* Whb  = (const float*)d_in[6];
  const float* bh   = (const float*)d_in[7];
  const float* Wy   = (const float*)d_in[8];   // [2,H,H]
  const float* Wyb  = (const float*)d_in[9];
  const float* by   = (const float*)d_in[10];
  const float* W1   = (const float*)d_in[11];  // [2,H,4H]
  const float* W1b  = (const float*)d_in[12];  // [2,4H]
  const float* W2   = (const float*)d_in[13];  // [2,4H,H]
  const float* W2b  = (const float*)d_in[14];
  const int*   xx   = (const int*)d_in[15];
  float* outF = (float*)d_out;
  (void)in_sizes; (void)n_in; (void)out_size; (void)ws_size;

  const size_t H2 = (size_t)H_*H_;
  char* p = (char*)d_ws;
  auto alloc = [&](size_t bytes)->void*{ void* r=(void*)p; p += (bytes+255)&~(size_t)255; return r; };

  // persistent buffers
  short* x_emb_bf = (short*)alloc((size_t)BT_*H_*2);
  short* xn0_bf   = (short*)alloc((size_t)BT_*H_*2);
  short* mg0_bf   = (short*)alloc((size_t)BT_*H_*2);
  short* ff0_bf   = (short*)alloc((size_t)BT_*H_*2);
  float* out0     = (float*)alloc((size_t)BT_*H_*4);
  short* xn1_bf   = (short*)alloc((size_t)BT_*H_*2);
  short* g1_bf    = (short*)alloc((size_t)BT_*H_*2);
  short* ffy1r_bf = (short*)alloc((size_t)BT_*H_*2);
  short* h0_all   = (short*)alloc((size_t)BT_*H_*2);
  short* h1_all   = (short*)alloc((size_t)BT_*H_*2);
  short* dec_bf   = (short*)alloc((size_t)BT_*H_*2);
  // zero-init region: states + flags
  char*  z0    = p;
  short* h0    = (short*)alloc((size_t)16*H_*2);
  short* h1    = (short*)alloc((size_t)16*H_*2);
  short* xcat0 = (short*)alloc((size_t)16*2*H_*2);
  short* xcat1 = (short*)alloc((size_t)16*2*H_*2);
  unsigned* fA0 = (unsigned*)alloc((size_t)T_*16*4);
  unsigned* fB0 = (unsigned*)alloc((size_t)T_*16*4);
  unsigned* fC0 = (unsigned*)alloc((size_t)T_*16*4);
  unsigned* fA1 = (unsigned*)alloc((size_t)T_*16*4);
  unsigned* fB1 = (unsigned*)alloc((size_t)T_*16*4);
  unsigned* fC1 = (unsigned*)alloc((size_t)T_*16*4);
  unsigned* dM  = (unsigned*)alloc((size_t)T_*4);
  size_t zbytes = (size_t)(p - z0);
  // weight region (dead after S9) — E_bf overlays it at the end
  char*  wreg = p;
  short* WmT = (short*)alloc(6*H2*2);              // [6][1024][1024]
  short* WhT = (short*)alloc(2*(size_t)H_*2*H_*2); // [2][1024][2048]
  short* WyT = (short*)alloc(2*H2*2);
  short* W1T = (short*)alloc(2*(size_t)4*H_*H_*2); // [2][4096][1024]
  short* W2T = (short*)alloc(2*(size_t)H_*4*H_*2); // [2][1024][4096]
  short* t1  = (short*)alloc((size_t)1024*4*H_*2); // FFN chunk buffer
  short* E_bf = (short*)wreg;                      // overlay: 62.5MB <= 64MB region

  hipMemsetAsync(z0, 0, zbytes, stream);

  // ---- precompute ----
  k_embed_ln<<<BT_,256,0,stream>>>(E, xx, ln_g, ln_b, x_emb_bf, xn0_bf);
  for(int i=0;i<6;i++)
    k_transpose_bf<<<dim3(32,32),256,0,stream>>>(Wm+i*H2, WmT+i*H2, H_, H_);
  for(int l=0;l<2;l++){
    k_transpose_bf<<<dim3(32,64),256,0,stream>>>(Wh+(size_t)l*2*H2, WhT+(size_t)l*2*H2, 2*H_, H_);
    k_transpose_bf<<<dim3(32,32),256,0,stream>>>(Wy+(size_t)l*H2, WyT+(size_t)l*H2, H_, H_);
    k_transpose_bf<<<dim3(128,32),256,0,stream>>>(W1+(size_t)l*4*H2, W1T+(size_t)l*4*H2, H_, 4*H_);
    k_transpose_bf<<<dim3(32,128),256,0,stream>>>(W2+(size_t)l*4*H2, W2T+(size_t)l*4*H2, 4*H_, H_);
  }
  // mg0 = 2sig(xn0 @ Wm[0,0]^T + b)
  k_mfma_nt<1,1,0><<<dim3(8,64),256,0,stream>>>(xn0_bf, WmT, Wmb, nullptr,
      nullptr,nullptr,nullptr, mg0_bf, BT_, H_, H_);
  // layer-0 FFN (chunked): ff0 = relu(xn0@W1_0+b)@W2_0 + b
  for(int cb=0;cb<4;cb++){
    k_mfma_nt<2,1,0><<<dim3(32,16),256,0,stream>>>(xn0_bf+(size_t)cb*1024*H_, W1T, W1b, nullptr,
        nullptr,nullptr,nullptr, t1, 1024, 4*H_, H_);
    k_mfma_nt<0,1,0><<<dim3(8,16),256,0,stream>>>(t1, W2T, W2b, nullptr,
        nullptr,nullptr,nullptr, ff0_bf+(size_t)cb*1024*H_, 1024, H_, 4*H_);
  }

  // ---- pipelined recurrence megakernel ----
  MegaArgs MA{};
  MA.xn0=xn0_bf; MA.mg0=mg0_bf;
  MA.WmT=WmT; MA.Wmb=Wmb; MA.WhT=WhT; MA.Whb=Whb; MA.bh=bh;
  MA.WyT=WyT; MA.Wyb=Wyb; MA.by=by;
  MA.xemb=x_emb_bf; MA.ff0=ff0_bf;
  MA.lng=ln_g+H_; MA.lnb=ln_b+H_;
  MA.out0=out0; MA.xn1=xn1_bf; MA.g1=g1_bf;
  MA.h0=h0; MA.h1=h1; MA.xcat0=xcat0; MA.xcat1=xcat1;
  MA.h0_all=h0_all; MA.h1_all=h1_all;
  MA.fA0=fA0; MA.fB0=fB0; MA.fC0=fC0; MA.fA1=fA1; MA.fB1=fB1; MA.fC1=fC1; MA.dM=dM;
  k_mega<<<64,512,0,stream>>>(MA);

  // ---- layer-1 FFN (chunked) with fused residual: ffy1r = FFN(xn1) + out0 + x_emb ----
  for(int cb=0;cb<4;cb++){
    k_mfma_nt<2,1,0><<<dim3(32,16),256,0,stream>>>(xn1_bf+(size_t)cb*1024*H_, W1T+(size_t)4*H2, W1b+4*H_, nullptr,
        nullptr,nullptr,nullptr, t1, 1024, 4*H_, H_);
    k_mfma_nt<0,1,0><<<dim3(8,16),256,0,stream>>>(t1, W2T+(size_t)4*H2, W2b+H_, nullptr,
        out0+(size_t)cb*1024*H_, x_emb_bf+(size_t)cb*1024*H_, nullptr,
        ffy1r_bf+(size_t)cb*1024*H_, 1024, H_, 4*H_);
  }

  // ---- S9: dec = h1_all@Wy1^T + Wyb1 + by1 + ffy1r  (bf16) ----
  k_mfma_nt<0,1,0><<<dim3(8,64),256,0,stream>>>(h1_all, WyT+H2, Wyb+H_, by+H_,
      nullptr, ffy1r_bf, nullptr, dec_bf, BT_, H_, H_);

  // ---- logits: E -> bf16 (overlays dead weight region), then big NT GEMM ----
  k_f2bf_vec<<<2048,256,0,stream>>>(E, E_bf, (V_*H_)/4);
  k_mfma_nt<0,0,1><<<dim3(V_/128, BT_/64),256,0,stream>>>(dec_bf, E_bf, nullptr, nullptr,
      nullptr,nullptr,nullptr, outF, BT_, V_, H_);
}

// Round 6
// 9376.640 us; speedup vs baseline: 12.0528x; 1.0259x over previous
//
#include <hip/hip_runtime.h>
#include <cstdint>
#include <cstring>
#include <cstddef>

#define L_ 2
#define H_ 1024
#define V_ 32000
#define B_ 16
#define T_ 256
#define BT_ 4096
#define EPS_ 1e-6f

typedef __attribute__((ext_vector_type(8))) short bf16x8;
typedef __attribute__((ext_vector_type(4))) short s16x4;
typedef __attribute__((ext_vector_type(4))) float f32x4;
typedef __attribute__((ext_vector_type(4))) int   i32x4;

__device__ __forceinline__ short f2bf(float f){
  uint32_t u; __builtin_memcpy(&u,&f,4);
  u += 0x7fffu + ((u>>16)&1u);
  return (short)(u>>16);
}
__device__ __forceinline__ float bf2f(short s){
  uint32_t u = ((uint32_t)(unsigned short)s)<<16;
  float f; __builtin_memcpy(&f,&u,4); return f;
}
__device__ __forceinline__ unsigned pack2(short a, short b){
  return (unsigned)(unsigned short)a | ((unsigned)(unsigned short)b << 16);
}

// ---------- coherent (cross-XCD, cache-bypassing) access helpers ----------
__device__ __forceinline__ void ld_sc_x4v(const void* p, i32x4* d){
  asm volatile(
    "global_load_dwordx4 %0, %4, off sc0 sc1\n\t"
    "global_load_dwordx4 %1, %4, off offset:16 sc0 sc1\n\t"
    "global_load_dwordx4 %2, %4, off offset:32 sc0 sc1\n\t"
    "global_load_dwordx4 %3, %4, off offset:48 sc0 sc1\n\t"
    "s_waitcnt vmcnt(0)"
    : "=&v"(d[0]),"=&v"(d[1]),"=&v"(d[2]),"=&v"(d[3])
    : "v"(p) : "memory");
}
__device__ __forceinline__ unsigned ld_sc_u32(const void* p){
  unsigned r;
  asm volatile("global_load_dword %0, %1, off sc0 sc1\n\ts_waitcnt vmcnt(0)"
               : "=&v"(r) : "v"(p) : "memory");
  return r;
}
__device__ __forceinline__ void st_sc_u32(void* p, unsigned v){
  asm volatile("global_store_dword %0, %1, off sc0 sc1" :: "v"(p), "v"(v) : "memory");
}
__device__ __forceinline__ void st_sc_x4(void* p, i32x4 v){
  asm volatile("global_store_dwordx4 %0, %1, off sc0 sc1" :: "v"(p), "v"(v) : "memory");
}
__device__ __forceinline__ void drain_vm(){
  asm volatile("s_waitcnt vmcnt(0)" ::: "memory");
}

// ---------- one-sided flag waits (monotonic, write-once per launch) ----------
__device__ __forceinline__ void wait_flags16(const unsigned* f){
  if(threadIdx.x < 64){
    const unsigned* p = f + (threadIdx.x & 15);
    while(ld_sc_u32(p)==0u) __builtin_amdgcn_s_sleep(1);
  }
  __syncthreads();
}
__device__ __forceinline__ void wait_flag1(const unsigned* f){
  if(threadIdx.x < 64){
    while(ld_sc_u32(f)==0u) __builtin_amdgcn_s_sleep(1);
  }
  __syncthreads();
}

// ---------------- block reduction over 256 threads ----------------
__device__ __forceinline__ float block_sum256(float v, float* s4){
#pragma unroll
  for(int o=32;o;o>>=1) v += __shfl_down(v,o,64);
  int lane = threadIdx.x & 63, w = threadIdx.x >> 6;
  if(lane==0) s4[w]=v;
  __syncthreads();
  float r = s4[0]+s4[1]+s4[2]+s4[3];
  __syncthreads();
  return r;
}

// ---------------- embedding gather + LayerNorm (layer 0), time-major rows ----------------
__global__ __launch_bounds__(256) void k_embed_ln(
    const float* __restrict__ E, const int* __restrict__ tok,
    const float* __restrict__ g, const float* __restrict__ b,
    short* __restrict__ x_emb_bf, short* __restrict__ xn_bf){
  __shared__ float s4[4];
  int row = blockIdx.x;              // row = t*16 + b
  int t = row >> 4, bb = row & 15;
  int tk = tok[bb*T_ + t];
  float4 v = ((const float4*)(E + (size_t)tk*H_))[threadIdx.x];
  float mean = block_sum256(v.x+v.y+v.z+v.w, s4) * (1.0f/H_);
  float d0=v.x-mean,d1=v.y-mean,d2=v.z-mean,d3=v.w-mean;
  float var = block_sum256(d0*d0+d1*d1+d2*d2+d3*d3, s4) * (1.0f/H_);
  float inv = 1.0f/(sqrtf(var)+EPS_);
  int c = threadIdx.x*4;
  s16x4 eb = {f2bf(v.x),f2bf(v.y),f2bf(v.z),f2bf(v.w)};
  ((s16x4*)(x_emb_bf + (size_t)row*H_))[threadIdx.x] = eb;
  s16x4 ob = {f2bf(g[c+0]*(d0*inv)+b[c+0]), f2bf(g[c+1]*(d1*inv)+b[c+1]),
              f2bf(g[c+2]*(d2*inv)+b[c+2]), f2bf(g[c+3]*(d3*inv)+b[c+3])};
  ((s16x4*)(xn_bf + (size_t)row*H_))[threadIdx.x] = ob;
}

// ---------------- transpose fp32 [R,C] -> bf16 [C,R] ----------------
__global__ __launch_bounds__(256) void k_transpose_bf(
    const float* __restrict__ src, short* __restrict__ dst, int Rr, int Cc){
  __shared__ float tile[32][33];
  int c0 = blockIdx.x*32, r0 = blockIdx.y*32;
  int tx = threadIdx.x & 31, ty = threadIdx.x >> 5;
#pragma unroll
  for(int i=0;i<32;i+=8)
    tile[ty+i][tx] = src[(size_t)(r0+ty+i)*Cc + c0+tx];
  __syncthreads();
#pragma unroll
  for(int i=0;i<32;i+=8)
    dst[(size_t)(c0+ty+i)*Rr + r0+tx] = f2bf(tile[tx][ty+i]);
}

// ---------------- fp32 -> bf16 flat convert ----------------
__global__ void k_f2bf_vec(const float* __restrict__ s, short* __restrict__ d, int n4){
  int i = blockIdx.x*blockDim.x + threadIdx.x;
  int st = gridDim.x*blockDim.x;
  for(; i<n4; i+=st){
    float4 v = ((const float4*)s)[i];
    s16x4 o = {f2bf(v.x),f2bf(v.y),f2bf(v.z),f2bf(v.w)};
    ((s16x4*)d)[i] = o;
  }
}

// ---------------- bf16 MFMA NT GEMM, generalized epilogue ----------------
template<int ACT, int OBF, int REMAP>
__global__ __launch_bounds__(256) void k_mfma_nt(
    const short* __restrict__ A, const short* __restrict__ Wt,
    const float* __restrict__ b1, const float* __restrict__ b2,
    const float* __restrict__ rf, const short* __restrict__ rb1,
    const short* __restrict__ rb2, void* __restrict__ out,
    int M, int N, int K){
  int wid = threadIdx.x >> 6, lane = threadIdx.x & 63;
  int m0 = blockIdx.y*64;
  int n0 = blockIdx.x*128 + wid*32;
  int lr = lane & 15, kq = lane >> 4;
  const short* Ap = A + (size_t)(m0+lr)*K + kq*8;
  const short* Bp = Wt + (size_t)(n0+lr)*K + kq*8;
  f32x4 acc[4][2];
#pragma unroll
  for(int i=0;i<4;i++)
#pragma unroll
    for(int j=0;j<2;j++) acc[i][j] = (f32x4)0.0f;
  for(int k=0;k<K;k+=32){
    bf16x8 a[4], b[2];
#pragma unroll
    for(int mi=0;mi<4;mi++) a[mi] = *(const bf16x8*)(Ap + (size_t)mi*16*K + k);
#pragma unroll
    for(int ni=0;ni<2;ni++) b[ni] = *(const bf16x8*)(Bp + (size_t)ni*16*K + k);
#pragma unroll
    for(int mi=0;mi<4;mi++)
#pragma unroll
      for(int ni=0;ni<2;ni++)
        acc[mi][ni] = __builtin_amdgcn_mfma_f32_16x16x32_bf16(a[mi], b[ni], acc[mi][ni], 0,0,0);
  }
#pragma unroll
  for(int mi=0;mi<4;mi++)
#pragma unroll
    for(int ni=0;ni<2;ni++)
#pragma unroll
      for(int r=0;r<4;r++){
        int row = m0 + mi*16 + kq*4 + r;
        int col = n0 + ni*16 + lr;
        float s = acc[mi][ni][r];
        if(b1) s += b1[col];
        if(b2) s += b2[col];
        if(ACT==1) s = 2.0f/(1.0f+expf(-s));
        else if(ACT==2) s = fmaxf(s, 0.0f);
        if(rf)  s += rf[(size_t)row*N+col];
        if(rb1) s += bf2f(rb1[(size_t)row*N+col]);
        if(rb2) s += bf2f(rb2[(size_t)row*N+col]);
        size_t orow = REMAP ? ((size_t)(row&15)*T_ + (row>>4)) : (size_t)row;
        if(OBF) ((short*)out)[orow*N+col] = f2bf(s);
        else    ((float*)out)[orow*N+col] = s;
      }
}

// ================= persistent pipelined megakernel =================
struct MegaArgs {
  const short *xn0, *mg0;      // [T][16][1024] precomputed, cached
  const short *WmT;            // [6][H][H]
  const float *Wmb;            // [6][H]
  const short *WhT;            // [2][H][2H]
  const float *Whb, *bh;       // [2][H]
  const short *WyT;            // [2][H][H]
  const float *Wyb, *by;
  const short *xemb, *ff0;     // [T*16][1024] bf16
  const float *lng, *lnb;      // layer-1 LN params
  float *out0;                 // [T*16][1024] f32 (nt stores; post-kernel + LN readback)
  short *xn1, *g1;             // sc (intra-kernel consumers)
  short *h0, *h1;              // [16][1024] states (sc)
  short *xcat0, *xcat1;        // [16][2048] (sc)
  short *h0_all, *h1_all;      // [T][16][1024] (sc)
  unsigned *fA0,*fB0,*fC0,*fA1,*fB1,*fC1,*dM;
};

struct RArgs {
  const short *xn, *gate, *Wm1T, *Wm2T, *WhT;
  const float *bm1, *bm2, *bh1, *bh2;
  short *h, *xcat, *h_all;
  unsigned *fA, *fB, *fC; const unsigned* dM;
};

#define RED(buf, ksv, c, re) buf[((((ksv)*4)+((c)>>4))*16 + (re))*16 + ((c)&15)]
#define SWI(row,e) ((e) ^ (((row)&7)<<3))

// recurrence group: 16 blocks, block owns 64 output cols; 8 waves = 4 colgrp x 2 Ksplit
template<int SC>
__device__ void recur_group(const RArgs& A, int blk, char* smem){
  short* x2   = (short*)smem;            // [16][1024] bf16, XOR-swizzled stash
  float* red1 = (float*)(smem + 32768);  // [2][4][16][16]
  float* red3 = (float*)(smem + 40960);
  const int tid=threadIdx.x, w=tid>>6, lane=tid&63, lr=lane&15, kq=lane>>4;
  const int cg=w&3, ks=w>>2;
  const int wcol = blk*64 + cg*16;
  const int re = tid>>5, cp = tid&31, c0 = cp*2, c1 = c0+1, gc0 = blk*64 + c0;
  const int rl = tid>>5, seg = tid&31;
  float p3_0=0.f, p3_1=0.f;

  for(int t=0;t<T_;++t){
    const short* xn_t = A.xn + (size_t)t*16384;
    const short* g_t  = A.gate + (size_t)t*16384;
    // ======== stage A: xm = xn .* 2sig((h.*g)@Wm1 + b) ========
    if(SC) wait_flag1(A.dM + t);
    if(t)  wait_flags16(A.fC + (size_t)(t-1)*16);
    {
      i32x4 hv[4], gv[4];
      ld_sc_x4v(A.h + (size_t)rl*1024 + seg*32, hv);
      if(SC) ld_sc_x4v(g_t + (size_t)rl*1024 + seg*32, gv);
      else { const i32x4* gp = (const i32x4*)(g_t + (size_t)rl*1024 + seg*32);
             gv[0]=gp[0]; gv[1]=gp[1]; gv[2]=gp[2]; gv[3]=gp[3]; }
#pragma unroll
      for(int u=0;u<4;u++){
        bf16x8 h8,g8,pr;
        __builtin_memcpy(&h8,&hv[u],16); __builtin_memcpy(&g8,&gv[u],16);
#pragma unroll
        for(int j=0;j<8;j++) pr[j] = f2bf(bf2f(h8[j])*bf2f(g8[j]));
        int e = seg*32+u*8;
        *(bf16x8*)(x2 + (size_t)rl*1024 + SWI(rl,e)) = pr;
      }
    }
    __syncthreads();
    {
      f32x4 acc = (f32x4)0.0f;
#pragma unroll
      for(int kk=0;kk<16;kk++){
        int k = ks*512 + kk*32 + kq*8;
        bf16x8 a = *(const bf16x8*)(x2 + (size_t)lr*1024 + SWI(lr,k));
        bf16x8 b = *(const bf16x8*)(A.Wm1T + (size_t)(wcol+lr)*1024 + k);
        acc = __builtin_amdgcn_mfma_f32_16x16x32_bf16(a,b,acc,0,0,0);
      }
#pragma unroll
      for(int r=0;r<4;r++) RED(red1,ks,cg*16+lr,kq*4+r) = acc[r];
    }
    __syncthreads();
    {
      float z0 = RED(red1,0,c0,re) + RED(red1,1,c0,re);
      float z1 = RED(red1,0,c1,re) + RED(red1,1,c1,re);
      float ga0 = 2.f/(1.f+expf(-(z0 + A.bm1[gc0])));
      float ga1 = 2.f/(1.f+expf(-(z1 + A.bm1[gc0+1])));
      unsigned xp;
      if(SC) xp = ld_sc_u32(xn_t + (size_t)re*1024 + gc0);
      else   xp = *(const unsigned*)(xn_t + (size_t)re*1024 + gc0);
      float x0 = bf2f((short)(xp&0xffff)), x1 = bf2f((short)(xp>>16));
      st_sc_u32(A.xcat + (size_t)re*2048 + gc0, pack2(f2bf(x0*ga0), f2bf(x1*ga1)));
    }
    drain_vm(); __syncthreads();
    if(tid==0) st_sc_u32(A.fA + (size_t)t*16 + blk, 1u);
    wait_flags16(A.fA + (size_t)t*16);
    // ======== stage B: hm = (h.*g) .* 2sig(xm@Wm2 + b); p3 = xm@Wh_top ========
    unsigned hp = ld_sc_u32(A.h + (size_t)re*1024 + gc0);
    unsigned gp2;
    if(SC) gp2 = ld_sc_u32(g_t + (size_t)re*1024 + gc0);
    else   gp2 = *(const unsigned*)(g_t + (size_t)re*1024 + gc0);
    {
      i32x4 xv[4]; ld_sc_x4v(A.xcat + (size_t)rl*2048 + seg*32, xv);
#pragma unroll
      for(int u=0;u<4;u++)
        *(i32x4*)(x2 + (size_t)rl*1024 + SWI(rl,seg*32+u*8)) = xv[u];
    }
    __syncthreads();
    {
      f32x4 acc2=(f32x4)0.0f, acc3=(f32x4)0.0f;
#pragma unroll
      for(int kk=0;kk<16;kk++){
        int k = ks*512 + kk*32 + kq*8;
        bf16x8 a  = *(const bf16x8*)(x2 + (size_t)lr*1024 + SWI(lr,k));
        bf16x8 b2 = *(const bf16x8*)(A.Wm2T + (size_t)(wcol+lr)*1024 + k);
        bf16x8 b3 = *(const bf16x8*)(A.WhT  + (size_t)(wcol+lr)*2048 + k);
        acc2 = __builtin_amdgcn_mfma_f32_16x16x32_bf16(a,b2,acc2,0,0,0);
        acc3 = __builtin_amdgcn_mfma_f32_16x16x32_bf16(a,b3,acc3,0,0,0);
      }
#pragma unroll
      for(int r=0;r<4;r++){
        RED(red1,ks,cg*16+lr,kq*4+r) = acc2[r];
        RED(red3,ks,cg*16+lr,kq*4+r) = acc3[r];
      }
    }
    __syncthreads();
    {
      float z0 = RED(red1,0,c0,re) + RED(red1,1,c0,re);
      float z1 = RED(red1,0,c1,re) + RED(red1,1,c1,re);
      p3_0 = RED(red3,0,c0,re) + RED(red3,1,c0,re);
      p3_1 = RED(red3,0,c1,re) + RED(red3,1,c1,re);
      float ga0 = 2.f/(1.f+expf(-(z0 + A.bm2[gc0])));
      float ga1 = 2.f/(1.f+expf(-(z1 + A.bm2[gc0+1])));
      float hv0 = bf2f((short)(hp&0xffff)) * bf2f((short)(gp2&0xffff)) * ga0;
      float hv1 = bf2f((short)(hp>>16))    * bf2f((short)(gp2>>16))    * ga1;
      st_sc_u32(A.xcat + (size_t)re*2048 + 1024 + gc0, pack2(f2bf(hv0), f2bf(hv1)));
    }
    drain_vm(); __syncthreads();
    if(tid==0) st_sc_u32(A.fB + (size_t)t*16 + blk, 1u);
    wait_flags16(A.fB + (size_t)t*16);
    // ======== stage C: h' = tanh(p3 + hm@Wh_bot + bh1 + bh2) ========
    {
      i32x4 xv[4]; ld_sc_x4v(A.xcat + (size_t)rl*2048 + 1024 + seg*32, xv);
#pragma unroll
      for(int u=0;u<4;u++)
        *(i32x4*)(x2 + (size_t)rl*1024 + SWI(rl,seg*32+u*8)) = xv[u];
    }
    __syncthreads();
    {
      f32x4 acc = (f32x4)0.0f;
#pragma unroll
      for(int kk=0;kk<16;kk++){
        int k = ks*512 + kk*32 + kq*8;
        bf16x8 a = *(const bf16x8*)(x2 + (size_t)lr*1024 + SWI(lr,k));
        bf16x8 b = *(const bf16x8*)(A.WhT + (size_t)(wcol+lr)*2048 + 1024 + k);
        acc = __builtin_amdgcn_mfma_f32_16x16x32_bf16(a,b,acc,0,0,0);
      }
#pragma unroll
      for(int r=0;r<4;r++) RED(red1,ks,cg*16+lr,kq*4+r) = acc[r];
    }
    __syncthreads();
    {
      float z0 = RED(red1,0,c0,re) + RED(red1,1,c0,re) + p3_0 + A.bh1[gc0]   + A.bh2[gc0];
      float z1 = RED(red1,0,c1,re) + RED(red1,1,c1,re) + p3_1 + A.bh1[gc0+1] + A.bh2[gc0+1];
      unsigned pk = pack2(f2bf(tanhf(z0)), f2bf(tanhf(z1)));
      st_sc_u32(A.h + (size_t)re*1024 + gc0, pk);
      st_sc_u32(A.h_all + (size_t)t*16384 + (size_t)re*1024 + gc0, pk);
    }
    drain_vm(); __syncthreads();
    if(tid==0) st_sc_u32(A.fC + (size_t)t*16 + blk, 1u);
  }
}

// middle group: 32 blocks, block m handles t = m, m+32, ... fully locally (no barriers)
// ALL streaming traffic (weights, xemb, ff0, out0) is NON-TEMPORAL so it cannot
// evict the recurrence groups' L2-resident weight slices.
__device__ void middle_group(const MegaArgs& M, int m, char* smem){
  short* stash   = (short*)smem;            // [16][1024] bf16 swizzled (A operand)
  short* staging = (short*)(smem + 32768);  // [16][1024] bf16 (g1 pack)
  const size_t H2 = (size_t)H_*H_;
  const short* WgT = M.WmT + 3*H2;
  const float* bm0 = M.Wmb + 3*H_;
  const int tid=threadIdx.x, w=tid>>6, lane=tid&63, lr=lane&15, kq=lane>>4;
  const int rl=tid>>5, seg=tid&31;
  const int wc = w*128;
  for(int t=m; t<T_; t+=32){
    wait_flags16(M.fC0 + (size_t)t*16);
    { // stash h0[t]
      i32x4 hv[4]; ld_sc_x4v(M.h0_all + (size_t)t*16384 + (size_t)rl*1024 + seg*32, hv);
#pragma unroll
      for(int u=0;u<4;u++)
        *(i32x4*)(stash + (size_t)rl*1024 + SWI(rl,seg*32+u*8)) = hv[u];
    }
    __syncthreads();
    { // GEMM1: out0 = h0@Wy0 + wyb + by + x_emb + ff0  (nt f32 stores)
      f32x4 acc[8];
#pragma unroll
      for(int n=0;n<8;n++) acc[n]=(f32x4)0.0f;
      for(int kk=0;kk<32;kk++){
        int k = kk*32 + kq*8;
        bf16x8 a = *(const bf16x8*)(stash + (size_t)lr*1024 + SWI(lr,k));
#pragma unroll
        for(int n=0;n<8;n++){
          bf16x8 b = __builtin_nontemporal_load(
              (const bf16x8*)(M.WyT + (size_t)(wc+n*16+lr)*1024 + k));
          acc[n] = __builtin_amdgcn_mfma_f32_16x16x32_bf16(a,b,acc[n],0,0,0);
        }
      }
#pragma unroll
      for(int n=0;n<8;n++)
#pragma unroll
        for(int r=0;r<4;r++){
          int row = kq*4+r, col = wc+n*16+lr;
          size_t gi = (size_t)t*16384 + (size_t)row*1024 + col;
          float v = acc[n][r] + M.Wyb[col] + M.by[col]
                  + bf2f(__builtin_nontemporal_load(M.xemb + gi))
                  + bf2f(__builtin_nontemporal_load(M.ff0 + gi));
          __builtin_nontemporal_store(v, M.out0 + gi);
        }
    }
    drain_vm(); __syncthreads();
    // LN: wave handles rows 2w, 2w+1 (reads back own block's out0)
#pragma unroll
    for(int rr=0; rr<2; rr++){
      int row = w*2+rr;
      const float* orow = M.out0 + (size_t)t*16384 + (size_t)row*1024;
      float pv[16];
#pragma unroll
      for(int i2=0;i2<4;i2++){
        float4 v4 = *(const float4*)(orow + lane*16 + i2*4);
        pv[i2*4+0]=v4.x; pv[i2*4+1]=v4.y; pv[i2*4+2]=v4.z; pv[i2*4+3]=v4.w;
      }
      float s=0.f,q=0.f;
#pragma unroll
      for(int i=0;i<16;i++){ s += pv[i]; q += pv[i]*pv[i]; }
#pragma unroll
      for(int o=32;o;o>>=1){ s += __shfl_down(s,o,64); q += __shfl_down(q,o,64); }
      s = __shfl(s,0,64); q = __shfl(q,0,64);
      float mu = s*(1.f/1024.f);
      float sg = sqrtf(fmaxf(q*(1.f/1024.f) - mu*mu, 0.f));
      float inv = 1.f/(sg + EPS_);
      short xb[16];
#pragma unroll
      for(int i=0;i<16;i++){
        int c = lane*16+i;
        xb[i] = f2bf(M.lng[c]*((pv[i]-mu)*inv) + M.lnb[c]);
      }
      i32x4 v0, v1;
#pragma unroll
      for(int j=0;j<4;j++){
        v0[j] = (int)pack2(xb[2*j],   xb[2*j+1]);
        v1[j] = (int)pack2(xb[8+2*j], xb[9+2*j]);
      }
      short* xrow = M.xn1 + (size_t)t*16384 + (size_t)row*1024;
      st_sc_x4(xrow + lane*16, v0);
      st_sc_x4(xrow + lane*16 + 8, v1);
      *(i32x4*)(stash + (size_t)row*1024 + SWI(row,lane*16))   = v0;
      *(i32x4*)(stash + (size_t)row*1024 + SWI(row,lane*16+8)) = v1;
    }
    __syncthreads();
    { // GEMM2: g1 = 2sig(xn1@Wm[1,0] + b)
      f32x4 acg[8];
#pragma unroll
      for(int n=0;n<8;n++) acg[n]=(f32x4)0.0f;
      for(int kk=0;kk<32;kk++){
        int k = kk*32 + kq*8;
        bf16x8 a = *(const bf16x8*)(stash + (size_t)lr*1024 + SWI(lr,k));
#pragma unroll
        for(int n=0;n<8;n++){
          bf16x8 b = __builtin_nontemporal_load(
              (const bf16x8*)(WgT + (size_t)(wc+n*16+lr)*1024 + k));
          acg[n] = __builtin_amdgcn_mfma_f32_16x16x32_bf16(a,b,acg[n],0,0,0);
        }
      }
#pragma unroll
      for(int n=0;n<8;n++)
#pragma unroll
        for(int r=0;r<4;r++){
          int row = kq*4+r, col = wc+n*16+lr;
          float gte = 2.f/(1.f+expf(-(acg[n][r] + bm0[col])));
          staging[(size_t)row*1024 + col] = f2bf(gte);
        }
    }
    __syncthreads();
    {
      short* grow = M.g1 + (size_t)t*16384 + (size_t)rl*1024 + seg*32;
#pragma unroll
      for(int u=0;u<4;u++){
        i32x4 g4 = *(const i32x4*)(staging + (size_t)rl*1024 + seg*32 + u*8);
        st_sc_x4(grow + u*8, g4);
      }
    }
    drain_vm(); __syncthreads();
    if(tid==0) st_sc_u32(M.dM + t, 1u);
  }
}

__global__ __launch_bounds__(512,1) void k_mega(MegaArgs M){
  __shared__ char smem[65536];
  const size_t H2 = (size_t)H_*H_;
  int b = blockIdx.x;
  if(b < 16){
    RArgs R{M.xn0, M.mg0, M.WmT+1*H2, M.WmT+2*H2, M.WhT,
            M.Wmb+1*H_, M.Wmb+2*H_, M.Whb, M.bh,
            M.h0, M.xcat0, M.h0_all, M.fA0, M.fB0, M.fC0, nullptr};
    recur_group<0>(R, b, smem);
  } else if(b < 48){
    middle_group(M, b-16, smem);
  } else {
    RArgs R{M.xn1, M.g1, M.WmT+4*H2, M.WmT+5*H2, M.WhT+2*H2,
            M.Wmb+4*H_, M.Wmb+5*H_, M.Whb+H_, M.bh+H_,
            M.h1, M.xcat1, M.h1_all, M.fA1, M.fB1, M.fC1, M.dM};
    recur_group<1>(R, b-48, smem);
  }
}

extern "C" void kernel_launch(void* const* d_in, const int* in_sizes, int n_in,
                              void* d_out, int out_size, void* d_ws, size_t ws_size,
                              hipStream_t stream){
  const float* E    = (const float*)d_in[0];
  const float* ln_g = (const float*)d_in[1];
  const float* ln_b = (const float*)d_in[2];
  const float* Wm   = (const float*)d_in[3];   // [2,3,H,H]
  const float* Wmb  = (const float*)d_in[4];   // [2,3,H]
  const float* Wh   = (const float*)d_in[5];   // [2,2H,H]
  const float* Whb  = (const float*)d_in[6];
  const float* bh   = (const float*)d_in[7];
  const float* Wy   = (const float*)d_in[8];   // [2,H,H]
  const float* Wyb  = (const float*)d_in[9];
  const float* by   = (const float*)d_in[10];
  const float* W1   = (const float*)d_in[11];  // [2,H,4H]
  const float* W1b  = (const float*)d_in[12];  // [2,4H]
  const float* W2   = (const float*)d_in[13];  // [2,4H,H]
  const float* W2b  = (const float*)d_in[14];
  const int*   xx   = (const int*)d_in[15];
  float* outF = (float*)d_out;
  (void)in_sizes; (void)n_in; (void)out_size; (void)ws_size;

  const size_t H2 = (size_t)H_*H_;
  char* p = (char*)d_ws;
  auto alloc = [&](size_t bytes)->void*{ void* r=(void*)p; p += (bytes+255)&~(size_t)255; return r; };

  // persistent buffers
  short* x_emb_bf = (short*)alloc((size_t)BT_*H_*2);
  short* xn0_bf   = (short*)alloc((size_t)BT_*H_*2);
  short* mg0_bf   = (short*)alloc((size_t)BT_*H_*2);
  short* ff0_bf   = (short*)alloc((size_t)BT_*H_*2);
  float* out0     = (float*)alloc((size_t)BT_*H_*4);
  short* xn1_bf   = (short*)alloc((size_t)BT_*H_*2);
  short* g1_bf    = (short*)alloc((size_t)BT_*H_*2);
  short* ffy1r_bf = (short*)alloc((size_t)BT_*H_*2);
  short* h0_all   = (short*)alloc((size_t)BT_*H_*2);
  short* h1_all   = (short*)alloc((size_t)BT_*H_*2);
  short* dec_bf   = (short*)alloc((size_t)BT_*H_*2);
  // zero-init region: states + flags
  char*  z0    = p;
  short* h0    = (short*)alloc((size_t)16*H_*2);
  short* h1    = (short*)alloc((size_t)16*H_*2);
  short* xcat0 = (short*)alloc((size_t)16*2*H_*2);
  short* xcat1 = (short*)alloc((size_t)16*2*H_*2);
  unsigned* fA0 = (unsigned*)alloc((size_t)T_*16*4);
  unsigned* fB0 = (unsigned*)alloc((size_t)T_*16*4);
  unsigned* fC0 = (unsigned*)alloc((size_t)T_*16*4);
  unsigned* fA1 = (unsigned*)alloc((size_t)T_*16*4);
  unsigned* fB1 = (unsigned*)alloc((size_t)T_*16*4);
  unsigned* fC1 = (unsigned*)alloc((size_t)T_*16*4);
  unsigned* dM  = (unsigned*)alloc((size_t)T_*4);
  size_t zbytes = (size_t)(p - z0);
  // weight region (dead after S9) — E_bf overlays it at the end
  char*  wreg = p;
  short* WmT = (short*)alloc(6*H2*2);              // [6][1024][1024]
  short* WhT = (short*)alloc(2*(size_t)H_*2*H_*2); // [2][1024][2048]
  short* WyT = (short*)alloc(2*H2*2);
  short* W1T = (short*)alloc(2*(size_t)4*H_*H_*2); // [2][4096][1024]
  short* W2T = (short*)alloc(2*(size_t)H_*4*H_*2); // [2][1024][4096]
  short* t1  = (short*)alloc((size_t)1024*4*H_*2); // FFN chunk buffer
  short* E_bf = (short*)wreg;                      // overlay: 62.5MB <= 64MB region

  hipMemsetAsync(z0, 0, zbytes, stream);

  // ---- precompute ----
  k_embed_ln<<<BT_,256,0,stream>>>(E, xx, ln_g, ln_b, x_emb_bf, xn0_bf);
  for(int i=0;i<6;i++)
    k_transpose_bf<<<dim3(32,32),256,0,stream>>>(Wm+i*H2, WmT+i*H2, H_, H_);
  for(int l=0;l<2;l++){
    k_transpose_bf<<<dim3(32,64),256,0,stream>>>(Wh+(size_t)l*2*H2, WhT+(size_t)l*2*H2, 2*H_, H_);
    k_transpose_bf<<<dim3(32,32),256,0,stream>>>(Wy+(size_t)l*H2, WyT+(size_t)l*H2, H_, H_);
    k_transpose_bf<<<dim3(128,32),256,0,stream>>>(W1+(size_t)l*4*H2, W1T+(size_t)l*4*H2, H_, 4*H_);
    k_transpose_bf<<<dim3(32,128),256,0,stream>>>(W2+(size_t)l*4*H2, W2T+(size_t)l*4*H2, 4*H_, H_);
  }
  // mg0 = 2sig(xn0 @ Wm[0,0]^T + b)
  k_mfma_nt<1,1,0><<<dim3(8,64),256,0,stream>>>(xn0_bf, WmT, Wmb, nullptr,
      nullptr,nullptr,nullptr, mg0_bf, BT_, H_, H_);
  // layer-0 FFN (chunked): ff0 = relu(xn0@W1_0+b)@W2_0 + b
  for(int cb=0;cb<4;cb++){
    k_mfma_nt<2,1,0><<<dim3(32,16),256,0,stream>>>(xn0_bf+(size_t)cb*1024*H_, W1T, W1b, nullptr,
        nullptr,nullptr,nullptr, t1, 1024, 4*H_, H_);
    k_mfma_nt<0,1,0><<<dim3(8,16),256,0,stream>>>(t1, W2T, W2b, nullptr,
        nullptr,nullptr,nullptr, ff0_bf+(size_t)cb*1024*H_, 1024, H_, 4*H_);
  }

  // ---- pipelined recurrence megakernel ----
  MegaArgs MA{};
  MA.xn0=xn0_bf; MA.mg0=mg0_bf;
  MA.WmT=WmT; MA.Wmb=Wmb; MA.WhT=WhT; MA.Whb=Whb; MA.bh=bh;
  MA.WyT=WyT; MA.Wyb=Wyb; MA.by=by;
  MA.xemb=x_emb_bf; MA.ff0=ff0_bf;
  MA.lng=ln_g+H_; MA.lnb=ln_b+H_;
  MA.out0=out0; MA.xn1=xn1_bf; MA.g1=g1_bf;
  MA.h0=h0; MA.h1=h1; MA.xcat0=xcat0; MA.xcat1=xcat1;
  MA.h0_all=h0_all; MA.h1_all=h1_all;
  MA.fA0=fA0; MA.fB0=fB0; MA.fC0=fC0; MA.fA1=fA1; MA.fB1=fB1; MA.fC1=fC1; MA.dM=dM;
  k_mega<<<64,512,0,stream>>>(MA);

  // ---- layer-1 FFN (chunked) with fused residual: ffy1r = FFN(xn1) + out0 + x_emb ----
  for(int cb=0;cb<4;cb++){
    k_mfma_nt<2,1,0><<<dim3(32,16),256,0,stream>>>(xn1_bf+(size_t)cb*1024*H_, W1T+(size_t)4*H2, W1b+4*H_, nullptr,
        nullptr,nullptr,nullptr, t1, 1024, 4*H_, H_);
    k_mfma_nt<0,1,0><<<dim3(8,16),256,0,stream>>>(t1, W2T+(size_t)4*H2, W2b+H_, nullptr,
        out0+(size_t)cb*1024*H_, x_emb_bf+(size_t)cb*1024*H_, nullptr,
        ffy1r_bf+(size_t)cb*1024*H_, 1024, H_, 4*H_);
  }

  // ---- S9: dec = h1_all@Wy1^T + Wyb1 + by1 + ffy1r  (bf16) ----
  k_mfma_nt<0,1,0><<<dim3(8,64),256,0,stream>>>(h1_all, WyT+H2, Wyb+H_, by+H_,
      nullptr, ffy1r_bf, nullptr, dec_bf, BT_, H_, H_);

  // ---- logits: E -> bf16 (overlays dead weight region), then big NT GEMM ----
  k_f2bf_vec<<<2048,256,0,stream>>>(E, E_bf, (V_*H_)/4);
  k_mfma_nt<0,0,1><<<dim3(V_/128, BT_/64),256,0,stream>>>(dec_bf, E_bf, nullptr, nullptr,
      nullptr,nullptr,nullptr, outF, BT_, V_, H_);
}

// Round 7
// 9367.056 us; speedup vs baseline: 12.0651x; 1.0010x over previous
//
#include <hip/hip_runtime.h>
#include <cstdint>
#include <cstring>
#include <cstddef>

#define L_ 2
#define H_ 1024
#define V_ 32000
#define B_ 16
#define T_ 256
#define BT_ 4096
#define EPS_ 1e-6f
#define NMID 96
#define GRID_ (16 + NMID + 16)

typedef __attribute__((ext_vector_type(8))) short bf16x8;
typedef __attribute__((ext_vector_type(4))) short s16x4;
typedef __attribute__((ext_vector_type(4))) float f32x4;
typedef __attribute__((ext_vector_type(4))) int   i32x4;

__device__ __forceinline__ short f2bf(float f){
  uint32_t u; __builtin_memcpy(&u,&f,4);
  u += 0x7fffu + ((u>>16)&1u);
  return (short)(u>>16);
}
__device__ __forceinline__ float bf2f(short s){
  uint32_t u = ((uint32_t)(unsigned short)s)<<16;
  float f; __builtin_memcpy(&f,&u,4); return f;
}
__device__ __forceinline__ unsigned pack2(short a, short b){
  return (unsigned)(unsigned short)a | ((unsigned)(unsigned short)b << 16);
}

// ---------- coherent (cross-XCD, cache-bypassing) access helpers ----------
__device__ __forceinline__ void ld_sc_x4v(const void* p, i32x4* d){
  asm volatile(
    "global_load_dwordx4 %0, %4, off sc0 sc1\n\t"
    "global_load_dwordx4 %1, %4, off offset:16 sc0 sc1\n\t"
    "global_load_dwordx4 %2, %4, off offset:32 sc0 sc1\n\t"
    "global_load_dwordx4 %3, %4, off offset:48 sc0 sc1\n\t"
    "s_waitcnt vmcnt(0)"
    : "=&v"(d[0]),"=&v"(d[1]),"=&v"(d[2]),"=&v"(d[3])
    : "v"(p) : "memory");
}
__device__ __forceinline__ unsigned ld_sc_u32(const void* p){
  unsigned r;
  asm volatile("global_load_dword %0, %1, off sc0 sc1\n\ts_waitcnt vmcnt(0)"
               : "=&v"(r) : "v"(p) : "memory");
  return r;
}
__device__ __forceinline__ void st_sc_u32(void* p, unsigned v){
  asm volatile("global_store_dword %0, %1, off sc0 sc1" :: "v"(p), "v"(v) : "memory");
}
__device__ __forceinline__ void st_sc_x4(void* p, i32x4 v){
  asm volatile("global_store_dwordx4 %0, %1, off sc0 sc1" :: "v"(p), "v"(v) : "memory");
}
__device__ __forceinline__ void drain_vm(){
  asm volatile("s_waitcnt vmcnt(0)" ::: "memory");
}

// ---------- one-sided flag waits (monotonic, write-once per launch) ----------
__device__ __forceinline__ void wait_flags16(const unsigned* f){
  if(threadIdx.x < 64){
    const unsigned* p = f + (threadIdx.x & 15);
    while(ld_sc_u32(p)==0u) __builtin_amdgcn_s_sleep(1);
  }
  __syncthreads();
}
__device__ __forceinline__ void wait_flag1(const unsigned* f){
  if(threadIdx.x < 64){
    while(ld_sc_u32(f)==0u) __builtin_amdgcn_s_sleep(1);
  }
  __syncthreads();
}

// ---------------- block reduction over 256 threads ----------------
__device__ __forceinline__ float block_sum256(float v, float* s4){
#pragma unroll
  for(int o=32;o;o>>=1) v += __shfl_down(v,o,64);
  int lane = threadIdx.x & 63, w = threadIdx.x >> 6;
  if(lane==0) s4[w]=v;
  __syncthreads();
  float r = s4[0]+s4[1]+s4[2]+s4[3];
  __syncthreads();
  return r;
}

// ---------------- embedding gather + LayerNorm (layer 0), time-major rows ----------------
__global__ __launch_bounds__(256) void k_embed_ln(
    const float* __restrict__ E, const int* __restrict__ tok,
    const float* __restrict__ g, const float* __restrict__ b,
    short* __restrict__ x_emb_bf, short* __restrict__ xn_bf){
  __shared__ float s4[4];
  int row = blockIdx.x;              // row = t*16 + b
  int t = row >> 4, bb = row & 15;
  int tk = tok[bb*T_ + t];
  float4 v = ((const float4*)(E + (size_t)tk*H_))[threadIdx.x];
  float mean = block_sum256(v.x+v.y+v.z+v.w, s4) * (1.0f/H_);
  float d0=v.x-mean,d1=v.y-mean,d2=v.z-mean,d3=v.w-mean;
  float var = block_sum256(d0*d0+d1*d1+d2*d2+d3*d3, s4) * (1.0f/H_);
  float inv = 1.0f/(sqrtf(var)+EPS_);
  int c = threadIdx.x*4;
  s16x4 eb = {f2bf(v.x),f2bf(v.y),f2bf(v.z),f2bf(v.w)};
  ((s16x4*)(x_emb_bf + (size_t)row*H_))[threadIdx.x] = eb;
  s16x4 ob = {f2bf(g[c+0]*(d0*inv)+b[c+0]), f2bf(g[c+1]*(d1*inv)+b[c+1]),
              f2bf(g[c+2]*(d2*inv)+b[c+2]), f2bf(g[c+3]*(d3*inv)+b[c+3])};
  ((s16x4*)(xn_bf + (size_t)row*H_))[threadIdx.x] = ob;
}

// ---------------- transpose fp32 [R,C] -> bf16 [C,R] ----------------
__global__ __launch_bounds__(256) void k_transpose_bf(
    const float* __restrict__ src, short* __restrict__ dst, int Rr, int Cc){
  __shared__ float tile[32][33];
  int c0 = blockIdx.x*32, r0 = blockIdx.y*32;
  int tx = threadIdx.x & 31, ty = threadIdx.x >> 5;
#pragma unroll
  for(int i=0;i<32;i+=8)
    tile[ty+i][tx] = src[(size_t)(r0+ty+i)*Cc + c0+tx];
  __syncthreads();
#pragma unroll
  for(int i=0;i<32;i+=8)
    dst[(size_t)(c0+ty+i)*Rr + r0+tx] = f2bf(tile[tx][ty+i]);
}

// ---------------- fp32 -> bf16 flat convert ----------------
__global__ void k_f2bf_vec(const float* __restrict__ s, short* __restrict__ d, int n4){
  int i = blockIdx.x*blockDim.x + threadIdx.x;
  int st = gridDim.x*blockDim.x;
  for(; i<n4; i+=st){
    float4 v = ((const float4*)s)[i];
    s16x4 o = {f2bf(v.x),f2bf(v.y),f2bf(v.z),f2bf(v.w)};
    ((s16x4*)d)[i] = o;
  }
}

// ---------------- bf16 MFMA NT GEMM, generalized epilogue ----------------
template<int ACT, int OBF, int REMAP>
__global__ __launch_bounds__(256) void k_mfma_nt(
    const short* __restrict__ A, const short* __restrict__ Wt,
    const float* __restrict__ b1, const float* __restrict__ b2,
    const float* __restrict__ rf, const short* __restrict__ rb1,
    const short* __restrict__ rb2, void* __restrict__ out,
    int M, int N, int K){
  int wid = threadIdx.x >> 6, lane = threadIdx.x & 63;
  int m0 = blockIdx.y*64;
  int n0 = blockIdx.x*128 + wid*32;
  int lr = lane & 15, kq = lane >> 4;
  const short* Ap = A + (size_t)(m0+lr)*K + kq*8;
  const short* Bp = Wt + (size_t)(n0+lr)*K + kq*8;
  f32x4 acc[4][2];
#pragma unroll
  for(int i=0;i<4;i++)
#pragma unroll
    for(int j=0;j<2;j++) acc[i][j] = (f32x4)0.0f;
  for(int k=0;k<K;k+=32){
    bf16x8 a[4], b[2];
#pragma unroll
    for(int mi=0;mi<4;mi++) a[mi] = *(const bf16x8*)(Ap + (size_t)mi*16*K + k);
#pragma unroll
    for(int ni=0;ni<2;ni++) b[ni] = *(const bf16x8*)(Bp + (size_t)ni*16*K + k);
#pragma unroll
    for(int mi=0;mi<4;mi++)
#pragma unroll
      for(int ni=0;ni<2;ni++)
        acc[mi][ni] = __builtin_amdgcn_mfma_f32_16x16x32_bf16(a[mi], b[ni], acc[mi][ni], 0,0,0);
  }
#pragma unroll
  for(int mi=0;mi<4;mi++)
#pragma unroll
    for(int ni=0;ni<2;ni++)
#pragma unroll
      for(int r=0;r<4;r++){
        int row = m0 + mi*16 + kq*4 + r;
        int col = n0 + ni*16 + lr;
        float s = acc[mi][ni][r];
        if(b1) s += b1[col];
        if(b2) s += b2[col];
        if(ACT==1) s = 2.0f/(1.0f+expf(-s));
        else if(ACT==2) s = fmaxf(s, 0.0f);
        if(rf)  s += rf[(size_t)row*N+col];
        if(rb1) s += bf2f(rb1[(size_t)row*N+col]);
        if(rb2) s += bf2f(rb2[(size_t)row*N+col]);
        size_t orow = REMAP ? ((size_t)(row&15)*T_ + (row>>4)) : (size_t)row;
        if(OBF) ((short*)out)[orow*N+col] = f2bf(s);
        else    ((float*)out)[orow*N+col] = s;
      }
}

// ================= persistent pipelined megakernel =================
struct MegaArgs {
  const short *xn0, *mg0;      // [T][16][1024] precomputed, cached
  const short *WmT;            // [6][H][H]
  const float *Wmb;            // [6][H]
  const short *WhT;            // [2][H][2H]
  const float *Whb, *bh;       // [2][H]
  const short *WyT;            // [2][H][H]
  const float *Wyb, *by;
  const short *xemb, *ff0;     // [T*16][1024] bf16
  const float *lng, *lnb;      // layer-1 LN params
  float *out0;                 // [T*16][1024] f32 (nt stores; post-kernel + LN readback)
  short *xn1, *g1;             // sc (intra-kernel consumers)
  short *h0, *h1;              // [16][1024] states (sc)
  short *xcat0, *xcat1;        // [16][2048] (sc)
  short *h0_all, *h1_all;      // [T][16][1024] (sc)
  unsigned *fA0,*fB0,*fC0,*fA1,*fB1,*fC1,*dM;
};

struct RArgs {
  const short *xn, *gate, *Wm1T, *Wm2T, *WhT;
  const float *bm1, *bm2, *bh1, *bh2;
  short *h, *xcat, *h_all;
  unsigned *fA, *fB, *fC; const unsigned* dM;
};

#define RED(buf, ksv, c, re) buf[((((ksv)*4)+((c)>>4))*16 + (re))*16 + ((c)&15)]
#define SWI(row,e) ((e) ^ (((row)&7)<<3))

// recurrence group: 16 blocks, block owns 64 output cols; 8 waves = 4 colgrp x 2 Ksplit
template<int SC>
__device__ void recur_group(const RArgs& A, int blk, char* smem){
  short* x2   = (short*)smem;            // [16][1024] bf16, XOR-swizzled stash
  float* red1 = (float*)(smem + 32768);  // [2][4][16][16]
  float* red3 = (float*)(smem + 40960);
  const int tid=threadIdx.x, w=tid>>6, lane=tid&63, lr=lane&15, kq=lane>>4;
  const int cg=w&3, ks=w>>2;
  const int wcol = blk*64 + cg*16;
  const int re = tid>>5, cp = tid&31, c0 = cp*2, c1 = c0+1, gc0 = blk*64 + c0;
  const int rl = tid>>5, seg = tid&31;
  float p3_0=0.f, p3_1=0.f;

  for(int t=0;t<T_;++t){
    const short* xn_t = A.xn + (size_t)t*16384;
    const short* g_t  = A.gate + (size_t)t*16384;
    // ======== stage A: xm = xn .* 2sig((h.*g)@Wm1 + b) ========
    if(SC) wait_flag1(A.dM + t);
    if(t)  wait_flags16(A.fC + (size_t)(t-1)*16);
    {
      i32x4 hv[4], gv[4];
      ld_sc_x4v(A.h + (size_t)rl*1024 + seg*32, hv);
      if(SC) ld_sc_x4v(g_t + (size_t)rl*1024 + seg*32, gv);
      else { const i32x4* gp = (const i32x4*)(g_t + (size_t)rl*1024 + seg*32);
             gv[0]=gp[0]; gv[1]=gp[1]; gv[2]=gp[2]; gv[3]=gp[3]; }
#pragma unroll
      for(int u=0;u<4;u++){
        bf16x8 h8,g8,pr;
        __builtin_memcpy(&h8,&hv[u],16); __builtin_memcpy(&g8,&gv[u],16);
#pragma unroll
        for(int j=0;j<8;j++) pr[j] = f2bf(bf2f(h8[j])*bf2f(g8[j]));
        int e = seg*32+u*8;
        *(bf16x8*)(x2 + (size_t)rl*1024 + SWI(rl,e)) = pr;
      }
    }
    __syncthreads();
    {
      f32x4 acc = (f32x4)0.0f;
#pragma unroll
      for(int kk=0;kk<16;kk++){
        int k = ks*512 + kk*32 + kq*8;
        bf16x8 a = *(const bf16x8*)(x2 + (size_t)lr*1024 + SWI(lr,k));
        bf16x8 b = *(const bf16x8*)(A.Wm1T + (size_t)(wcol+lr)*1024 + k);
        acc = __builtin_amdgcn_mfma_f32_16x16x32_bf16(a,b,acc,0,0,0);
      }
#pragma unroll
      for(int r=0;r<4;r++) RED(red1,ks,cg*16+lr,kq*4+r) = acc[r];
    }
    __syncthreads();
    {
      float z0 = RED(red1,0,c0,re) + RED(red1,1,c0,re);
      float z1 = RED(red1,0,c1,re) + RED(red1,1,c1,re);
      float ga0 = 2.f/(1.f+expf(-(z0 + A.bm1[gc0])));
      float ga1 = 2.f/(1.f+expf(-(z1 + A.bm1[gc0+1])));
      unsigned xp;
      if(SC) xp = ld_sc_u32(xn_t + (size_t)re*1024 + gc0);
      else   xp = *(const unsigned*)(xn_t + (size_t)re*1024 + gc0);
      float x0 = bf2f((short)(xp&0xffff)), x1 = bf2f((short)(xp>>16));
      st_sc_u32(A.xcat + (size_t)re*2048 + gc0, pack2(f2bf(x0*ga0), f2bf(x1*ga1)));
    }
    drain_vm(); __syncthreads();
    if(tid==0) st_sc_u32(A.fA + (size_t)t*16 + blk, 1u);
    wait_flags16(A.fA + (size_t)t*16);
    // ======== stage B: hm = (h.*g) .* 2sig(xm@Wm2 + b); p3 = xm@Wh_top ========
    unsigned hp = ld_sc_u32(A.h + (size_t)re*1024 + gc0);
    unsigned gp2;
    if(SC) gp2 = ld_sc_u32(g_t + (size_t)re*1024 + gc0);
    else   gp2 = *(const unsigned*)(g_t + (size_t)re*1024 + gc0);
    {
      i32x4 xv[4]; ld_sc_x4v(A.xcat + (size_t)rl*2048 + seg*32, xv);
#pragma unroll
      for(int u=0;u<4;u++)
        *(i32x4*)(x2 + (size_t)rl*1024 + SWI(rl,seg*32+u*8)) = xv[u];
    }
    __syncthreads();
    {
      f32x4 acc2=(f32x4)0.0f, acc3=(f32x4)0.0f;
#pragma unroll
      for(int kk=0;kk<16;kk++){
        int k = ks*512 + kk*32 + kq*8;
        bf16x8 a  = *(const bf16x8*)(x2 + (size_t)lr*1024 + SWI(lr,k));
        bf16x8 b2 = *(const bf16x8*)(A.Wm2T + (size_t)(wcol+lr)*1024 + k);
        bf16x8 b3 = *(const bf16x8*)(A.WhT  + (size_t)(wcol+lr)*2048 + k);
        acc2 = __builtin_amdgcn_mfma_f32_16x16x32_bf16(a,b2,acc2,0,0,0);
        acc3 = __builtin_amdgcn_mfma_f32_16x16x32_bf16(a,b3,acc3,0,0,0);
      }
#pragma unroll
      for(int r=0;r<4;r++){
        RED(red1,ks,cg*16+lr,kq*4+r) = acc2[r];
        RED(red3,ks,cg*16+lr,kq*4+r) = acc3[r];
      }
    }
    __syncthreads();
    {
      float z0 = RED(red1,0,c0,re) + RED(red1,1,c0,re);
      float z1 = RED(red1,0,c1,re) + RED(red1,1,c1,re);
      p3_0 = RED(red3,0,c0,re) + RED(red3,1,c0,re);
      p3_1 = RED(red3,0,c1,re) + RED(red3,1,c1,re);
      float ga0 = 2.f/(1.f+expf(-(z0 + A.bm2[gc0])));
      float ga1 = 2.f/(1.f+expf(-(z1 + A.bm2[gc0+1])));
      float hv0 = bf2f((short)(hp&0xffff)) * bf2f((short)(gp2&0xffff)) * ga0;
      float hv1 = bf2f((short)(hp>>16))    * bf2f((short)(gp2>>16))    * ga1;
      st_sc_u32(A.xcat + (size_t)re*2048 + 1024 + gc0, pack2(f2bf(hv0), f2bf(hv1)));
    }
    drain_vm(); __syncthreads();
    if(tid==0) st_sc_u32(A.fB + (size_t)t*16 + blk, 1u);
    wait_flags16(A.fB + (size_t)t*16);
    // ======== stage C: h' = tanh(p3 + hm@Wh_bot + bh1 + bh2) ========
    {
      i32x4 xv[4]; ld_sc_x4v(A.xcat + (size_t)rl*2048 + 1024 + seg*32, xv);
#pragma unroll
      for(int u=0;u<4;u++)
        *(i32x4*)(x2 + (size_t)rl*1024 + SWI(rl,seg*32+u*8)) = xv[u];
    }
    __syncthreads();
    {
      f32x4 acc = (f32x4)0.0f;
#pragma unroll
      for(int kk=0;kk<16;kk++){
        int k = ks*512 + kk*32 + kq*8;
        bf16x8 a = *(const bf16x8*)(x2 + (size_t)lr*1024 + SWI(lr,k));
        bf16x8 b = *(const bf16x8*)(A.WhT + (size_t)(wcol+lr)*2048 + 1024 + k);
        acc = __builtin_amdgcn_mfma_f32_16x16x32_bf16(a,b,acc,0,0,0);
      }
#pragma unroll
      for(int r=0;r<4;r++) RED(red1,ks,cg*16+lr,kq*4+r) = acc[r];
    }
    __syncthreads();
    {
      float z0 = RED(red1,0,c0,re) + RED(red1,1,c0,re) + p3_0 + A.bh1[gc0]   + A.bh2[gc0];
      float z1 = RED(red1,0,c1,re) + RED(red1,1,c1,re) + p3_1 + A.bh1[gc0+1] + A.bh2[gc0+1];
      unsigned pk = pack2(f2bf(tanhf(z0)), f2bf(tanhf(z1)));
      st_sc_u32(A.h + (size_t)re*1024 + gc0, pk);
      st_sc_u32(A.h_all + (size_t)t*16384 + (size_t)re*1024 + gc0, pk);
    }
    drain_vm(); __syncthreads();
    if(tid==0) st_sc_u32(A.fC + (size_t)t*16 + blk, 1u);
  }
}

// middle group: NMID blocks, block m handles t = m, m+NMID, ... fully locally.
// ALL streaming traffic (weights, xemb, ff0, out0) is NON-TEMPORAL so it cannot
// evict the recurrence groups' L2-resident weight slices.
__device__ void middle_group(const MegaArgs& M, int m, char* smem){
  short* stash   = (short*)smem;            // [16][1024] bf16 swizzled (A operand)
  short* staging = (short*)(smem + 32768);  // [16][1024] bf16 (g1 pack)
  const size_t H2 = (size_t)H_*H_;
  const short* WgT = M.WmT + 3*H2;
  const float* bm0 = M.Wmb + 3*H_;
  const int tid=threadIdx.x, w=tid>>6, lane=tid&63, lr=lane&15, kq=lane>>4;
  const int rl=tid>>5, seg=tid&31;
  const int wc = w*128;
  for(int t=m; t<T_; t+=NMID){
    wait_flags16(M.fC0 + (size_t)t*16);
    { // stash h0[t]
      i32x4 hv[4]; ld_sc_x4v(M.h0_all + (size_t)t*16384 + (size_t)rl*1024 + seg*32, hv);
#pragma unroll
      for(int u=0;u<4;u++)
        *(i32x4*)(stash + (size_t)rl*1024 + SWI(rl,seg*32+u*8)) = hv[u];
    }
    __syncthreads();
    { // GEMM1: out0 = h0@Wy0 + wyb + by + x_emb + ff0  (nt f32 stores)
      f32x4 acc[8];
#pragma unroll
      for(int n=0;n<8;n++) acc[n]=(f32x4)0.0f;
      for(int kk=0;kk<32;kk++){
        int k = kk*32 + kq*8;
        bf16x8 a = *(const bf16x8*)(stash + (size_t)lr*1024 + SWI(lr,k));
#pragma unroll
        for(int n=0;n<8;n++){
          bf16x8 b = __builtin_nontemporal_load(
              (const bf16x8*)(M.WyT + (size_t)(wc+n*16+lr)*1024 + k));
          acc[n] = __builtin_amdgcn_mfma_f32_16x16x32_bf16(a,b,acc[n],0,0,0);
        }
      }
#pragma unroll
      for(int n=0;n<8;n++)
#pragma unroll
        for(int r=0;r<4;r++){
          int row = kq*4+r, col = wc+n*16+lr;
          size_t gi = (size_t)t*16384 + (size_t)row*1024 + col;
          float v = acc[n][r] + M.Wyb[col] + M.by[col]
                  + bf2f(__builtin_nontemporal_load(M.xemb + gi))
                  + bf2f(__builtin_nontemporal_load(M.ff0 + gi));
          __builtin_nontemporal_store(v, M.out0 + gi);
        }
    }
    drain_vm(); __syncthreads();
    // LN: wave handles rows 2w, 2w+1 (reads back own block's out0)
#pragma unroll
    for(int rr=0; rr<2; rr++){
      int row = w*2+rr;
      const float* orow = M.out0 + (size_t)t*16384 + (size_t)row*1024;
      float pv[16];
#pragma unroll
      for(int i2=0;i2<4;i2++){
        float4 v4 = *(const float4*)(orow + lane*16 + i2*4);
        pv[i2*4+0]=v4.x; pv[i2*4+1]=v4.y; pv[i2*4+2]=v4.z; pv[i2*4+3]=v4.w;
      }
      float s=0.f,q=0.f;
#pragma unroll
      for(int i=0;i<16;i++){ s += pv[i]; q += pv[i]*pv[i]; }
#pragma unroll
      for(int o=32;o;o>>=1){ s += __shfl_down(s,o,64); q += __shfl_down(q,o,64); }
      s = __shfl(s,0,64); q = __shfl(q,0,64);
      float mu = s*(1.f/1024.f);
      float sg = sqrtf(fmaxf(q*(1.f/1024.f) - mu*mu, 0.f));
      float inv = 1.f/(sg + EPS_);
      short xb[16];
#pragma unroll
      for(int i=0;i<16;i++){
        int c = lane*16+i;
        xb[i] = f2bf(M.lng[c]*((pv[i]-mu)*inv) + M.lnb[c]);
      }
      i32x4 v0, v1;
#pragma unroll
      for(int j=0;j<4;j++){
        v0[j] = (int)pack2(xb[2*j],   xb[2*j+1]);
        v1[j] = (int)pack2(xb[8+2*j], xb[9+2*j]);
      }
      short* xrow = M.xn1 + (size_t)t*16384 + (size_t)row*1024;
      st_sc_x4(xrow + lane*16, v0);
      st_sc_x4(xrow + lane*16 + 8, v1);
      *(i32x4*)(stash + (size_t)row*1024 + SWI(row,lane*16))   = v0;
      *(i32x4*)(stash + (size_t)row*1024 + SWI(row,lane*16+8)) = v1;
    }
    __syncthreads();
    { // GEMM2: g1 = 2sig(xn1@Wm[1,0] + b)
      f32x4 acg[8];
#pragma unroll
      for(int n=0;n<8;n++) acg[n]=(f32x4)0.0f;
      for(int kk=0;kk<32;kk++){
        int k = kk*32 + kq*8;
        bf16x8 a = *(const bf16x8*)(stash + (size_t)lr*1024 + SWI(lr,k));
#pragma unroll
        for(int n=0;n<8;n++){
          bf16x8 b = __builtin_nontemporal_load(
              (const bf16x8*)(WgT + (size_t)(wc+n*16+lr)*1024 + k));
          acg[n] = __builtin_amdgcn_mfma_f32_16x16x32_bf16(a,b,acg[n],0,0,0);
        }
      }
#pragma unroll
      for(int n=0;n<8;n++)
#pragma unroll
        for(int r=0;r<4;r++){
          int row = kq*4+r, col = wc+n*16+lr;
          float gte = 2.f/(1.f+expf(-(acg[n][r] + bm0[col])));
          staging[(size_t)row*1024 + col] = f2bf(gte);
        }
    }
    __syncthreads();
    {
      short* grow = M.g1 + (size_t)t*16384 + (size_t)rl*1024 + seg*32;
#pragma unroll
      for(int u=0;u<4;u++){
        i32x4 g4 = *(const i32x4*)(staging + (size_t)rl*1024 + seg*32 + u*8);
        st_sc_x4(grow + u*8, g4);
      }
    }
    drain_vm(); __syncthreads();
    if(tid==0) st_sc_u32(M.dM + t, 1u);
  }
}

__global__ __launch_bounds__(512,1) void k_mega(MegaArgs M){
  __shared__ char smem[65536];
  const size_t H2 = (size_t)H_*H_;
  int b = blockIdx.x;
  if(b < 16){
    RArgs R{M.xn0, M.mg0, M.WmT+1*H2, M.WmT+2*H2, M.WhT,
            M.Wmb+1*H_, M.Wmb+2*H_, M.Whb, M.bh,
            M.h0, M.xcat0, M.h0_all, M.fA0, M.fB0, M.fC0, nullptr};
    recur_group<0>(R, b, smem);
  } else if(b < 16+NMID){
    middle_group(M, b-16, smem);
  } else {
    RArgs R{M.xn1, M.g1, M.WmT+4*H2, M.WmT+5*H2, M.WhT+2*H2,
            M.Wmb+4*H_, M.Wmb+5*H_, M.Whb+H_, M.bh+H_,
            M.h1, M.xcat1, M.h1_all, M.fA1, M.fB1, M.fC1, M.dM};
    recur_group<1>(R, b-(16+NMID), smem);
  }
}

extern "C" void kernel_launch(void* const* d_in, const int* in_sizes, int n_in,
                              void* d_out, int out_size, void* d_ws, size_t ws_size,
                              hipStream_t stream){
  const float* E    = (const float*)d_in[0];
  const float* ln_g = (const float*)d_in[1];
  const float* ln_b = (const float*)d_in[2];
  const float* Wm   = (const float*)d_in[3];   // [2,3,H,H]
  const float* Wmb  = (const float*)d_in[4];   // [2,3,H]
  const float* Wh   = (const float*)d_in[5];   // [2,2H,H]
  const float* Whb  = (const float*)d_in[6];
  const float* bh   = (const float*)d_in[7];
  const float* Wy   = (const float*)d_in[8];   // [2,H,H]
  const float* Wyb  = (const float*)d_in[9];
  const float* by   = (const float*)d_in[10];
  const float* W1   = (const float*)d_in[11];  // [2,H,4H]
  const float* W1b  = (const float*)d_in[12];  // [2,4H]
  const float* W2   = (const float*)d_in[13];  // [2,4H,H]
  const float* W2b  = (const float*)d_in[14];
  const int*   xx   = (const int*)d_in[15];
  float* outF = (float*)d_out;
  (void)in_sizes; (void)n_in; (void)out_size; (void)ws_size;

  const size_t H2 = (size_t)H_*H_;
  char* p = (char*)d_ws;
  auto alloc = [&](size_t bytes)->void*{ void* r=(void*)p; p += (bytes+255)&~(size_t)255; return r; };

  // persistent buffers
  short* x_emb_bf = (short*)alloc((size_t)BT_*H_*2);
  short* xn0_bf   = (short*)alloc((size_t)BT_*H_*2);
  short* mg0_bf   = (short*)alloc((size_t)BT_*H_*2);
  short* ff0_bf   = (short*)alloc((size_t)BT_*H_*2);
  float* out0     = (float*)alloc((size_t)BT_*H_*4);
  short* xn1_bf   = (short*)alloc((size_t)BT_*H_*2);
  short* g1_bf    = (short*)alloc((size_t)BT_*H_*2);
  short* ffy1r_bf = (short*)alloc((size_t)BT_*H_*2);
  short* h0_all   = (short*)alloc((size_t)BT_*H_*2);
  short* h1_all   = (short*)alloc((size_t)BT_*H_*2);
  short* dec_bf   = (short*)alloc((size_t)BT_*H_*2);
  // zero-init region: states + flags
  char*  z0    = p;
  short* h0    = (short*)alloc((size_t)16*H_*2);
  short* h1    = (short*)alloc((size_t)16*H_*2);
  short* xcat0 = (short*)alloc((size_t)16*2*H_*2);
  short* xcat1 = (short*)alloc((size_t)16*2*H_*2);
  unsigned* fA0 = (unsigned*)alloc((size_t)T_*16*4);
  unsigned* fB0 = (unsigned*)alloc((size_t)T_*16*4);
  unsigned* fC0 = (unsigned*)alloc((size_t)T_*16*4);
  unsigned* fA1 = (unsigned*)alloc((size_t)T_*16*4);
  unsigned* fB1 = (unsigned*)alloc((size_t)T_*16*4);
  unsigned* fC1 = (unsigned*)alloc((size_t)T_*16*4);
  unsigned* dM  = (unsigned*)alloc((size_t)T_*4);
  size_t zbytes = (size_t)(p - z0);
  // weight region (dead after S9) — E_bf overlays it at the end
  char*  wreg = p;
  short* WmT = (short*)alloc(6*H2*2);              // [6][1024][1024]
  short* WhT = (short*)alloc(2*(size_t)H_*2*H_*2); // [2][1024][2048]
  short* WyT = (short*)alloc(2*H2*2);
  short* W1T = (short*)alloc(2*(size_t)4*H_*H_*2); // [2][4096][1024]
  short* W2T = (short*)alloc(2*(size_t)H_*4*H_*2); // [2][1024][4096]
  short* t1  = (short*)alloc((size_t)1024*4*H_*2); // FFN chunk buffer
  short* E_bf = (short*)wreg;                      // overlay: 62.5MB <= 64MB region

  hipMemsetAsync(z0, 0, zbytes, stream);

  // ---- precompute ----
  k_embed_ln<<<BT_,256,0,stream>>>(E, xx, ln_g, ln_b, x_emb_bf, xn0_bf);
  for(int i=0;i<6;i++)
    k_transpose_bf<<<dim3(32,32),256,0,stream>>>(Wm+i*H2, WmT+i*H2, H_, H_);
  for(int l=0;l<2;l++){
    k_transpose_bf<<<dim3(32,64),256,0,stream>>>(Wh+(size_t)l*2*H2, WhT+(size_t)l*2*H2, 2*H_, H_);
    k_transpose_bf<<<dim3(32,32),256,0,stream>>>(Wy+(size_t)l*H2, WyT+(size_t)l*H2, H_, H_);
    k_transpose_bf<<<dim3(128,32),256,0,stream>>>(W1+(size_t)l*4*H2, W1T+(size_t)l*4*H2, H_, 4*H_);
    k_transpose_bf<<<dim3(32,128),256,0,stream>>>(W2+(size_t)l*4*H2, W2T+(size_t)l*4*H2, 4*H_, H_);
  }
  // mg0 = 2sig(xn0 @ Wm[0,0]^T + b)
  k_mfma_nt<1,1,0><<<dim3(8,64),256,0,stream>>>(xn0_bf, WmT, Wmb, nullptr,
      nullptr,nullptr,nullptr, mg0_bf, BT_, H_, H_);
  // layer-0 FFN (chunked): ff0 = relu(xn0@W1_0+b)@W2_0 + b
  for(int cb=0;cb<4;cb++){
    k_mfma_nt<2,1,0><<<dim3(32,16),256,0,stream>>>(xn0_bf+(size_t)cb*1024*H_, W1T, W1b, nullptr,
        nullptr,nullptr,nullptr, t1, 1024, 4*H_, H_);
    k_mfma_nt<0,1,0><<<dim3(8,16),256,0,stream>>>(t1, W2T, W2b, nullptr,
        nullptr,nullptr,nullptr, ff0_bf+(size_t)cb*1024*H_, 1024, H_, 4*H_);
  }

  // ---- pipelined recurrence megakernel ----
  MegaArgs MA{};
  MA.xn0=xn0_bf; MA.mg0=mg0_bf;
  MA.WmT=WmT; MA.Wmb=Wmb; MA.WhT=WhT; MA.Whb=Whb; MA.bh=bh;
  MA.WyT=WyT; MA.Wyb=Wyb; MA.by=by;
  MA.xemb=x_emb_bf; MA.ff0=ff0_bf;
  MA.lng=ln_g+H_; MA.lnb=ln_b+H_;
  MA.out0=out0; MA.xn1=xn1_bf; MA.g1=g1_bf;
  MA.h0=h0; MA.h1=h1; MA.xcat0=xcat0; MA.xcat1=xcat1;
  MA.h0_all=h0_all; MA.h1_all=h1_all;
  MA.fA0=fA0; MA.fB0=fB0; MA.fC0=fC0; MA.fA1=fA1; MA.fB1=fB1; MA.fC1=fC1; MA.dM=dM;
  k_mega<<<GRID_,512,0,stream>>>(MA);

  // ---- layer-1 FFN (chunked) with fused residual: ffy1r = FFN(xn1) + out0 + x_emb ----
  for(int cb=0;cb<4;cb++){
    k_mfma_nt<2,1,0><<<dim3(32,16),256,0,stream>>>(xn1_bf+(size_t)cb*1024*H_, W1T+(size_t)4*H2, W1b+4*H_, nullptr,
        nullptr,nullptr,nullptr, t1, 1024, 4*H_, H_);
    k_mfma_nt<0,1,0><<<dim3(8,16),256,0,stream>>>(t1, W2T+(size_t)4*H2, W2b+H_, nullptr,
        out0+(size_t)cb*1024*H_, x_emb_bf+(size_t)cb*1024*H_, nullptr,
        ffy1r_bf+(size_t)cb*1024*H_, 1024, H_, 4*H_);
  }

  // ---- S9: dec = h1_all@Wy1^T + Wyb1 + by1 + ffy1r  (bf16) ----
  k_mfma_nt<0,1,0><<<dim3(8,64),256,0,stream>>>(h1_all, WyT+H2, Wyb+H_, by+H_,
      nullptr, ffy1r_bf, nullptr, dec_bf, BT_, H_, H_);

  // ---- logits: E -> bf16 (overlays dead weight region), then big NT GEMM ----
  k_f2bf_vec<<<2048,256,0,stream>>>(E, E_bf, (V_*H_)/4);
  k_mfma_nt<0,0,1><<<dim3(V_/128, BT_/64),256,0,stream>>>(dec_bf, E_bf, nullptr, nullptr,
      nullptr,nullptr,nullptr, outF, BT_, V_, H_);
}